// Round 10
// baseline (739.508 us; speedup 1.0000x reference)
//
#include <hip/hip_runtime.h>
#include <math.h>

#define B_ 16
#define S_ 2048
#define H_ 12
#define D_ 64
#define HID 768
#define A_ 40
#define SCALE_ 0.125f
#define CH1 8          // stage1 s-chunks per (b,h)
#define SUBT 64        // s per subtile
#define NSUB 4         // subtiles per block (256 s per block)
#define DROWS 4112     // padded dist rows (4095 real, zero-pad to cover PE tiles)

typedef __attribute__((ext_vector_type(8))) short short8v;    // 8 bf16 (4 VGPR)
typedef __attribute__((ext_vector_type(4))) float f32x4;
typedef __attribute__((ext_vector_type(16))) float f32x16;    // 32x32 MFMA C/D

__device__ __forceinline__ unsigned f2bf_bits(float x) {
    unsigned u = __float_as_uint(x);
    return (u + 0x7FFFu + ((u >> 16) & 1u)) >> 16;   // RTNE
}

__device__ __forceinline__ void split1(float v, unsigned short& h, unsigned short& l) {
    __bf16 bh = (__bf16)v;
    float hf = (float)bh;
    __bf16 bl = (__bf16)(v - hf);
    h = __builtin_bit_cast(unsigned short, bh);
    l = __builtin_bit_cast(unsigned short, bl);
}

// split 8 fp32 -> hi/lo bf16 via native __bf16 casts (RTNE)
__device__ __forceinline__ void split8c(const float* x, int4& hi, int4& lo) {
    unsigned h[8], l[8];
#pragma unroll
    for (int i = 0; i < 8; i++) {
        __bf16 bh = (__bf16)x[i];
        float hf = (float)bh;
        __bf16 bl = (__bf16)(x[i] - hf);
        h[i] = (unsigned)__builtin_bit_cast(unsigned short, bh);
        l[i] = (unsigned)__builtin_bit_cast(unsigned short, bl);
    }
    hi = make_int4((int)(h[0] | (h[1] << 16)), (int)(h[2] | (h[3] << 16)),
                   (int)(h[4] | (h[5] << 16)), (int)(h[6] | (h[7] << 16)));
    lo = make_int4((int)(l[0] | (l[1] << 16)), (int)(l[2] | (l[3] << 16)),
                   (int)(l[4] | (l[5] << 16)), (int)(l[6] | (l[7] << 16)));
}

// ---------------- W transpose + bf16 hi/lo split: Wt[z][n][k] ----------------
__global__ void wt_convert(const float* __restrict__ Wq, const float* __restrict__ Wk,
                           const float* __restrict__ Wv,
                           unsigned short* __restrict__ Wth, unsigned short* __restrict__ Wtl)
{
    int idx = blockIdx.x * 256 + threadIdx.x;          // 3 * 192 * 768
    if (idx >= 3 * 192 * 768) return;
    int n  = idx % 768;
    int kc = (idx / 768) % 192;
    int z  = idx / (768 * 192);
    const float* W = (z == 0) ? Wq : (z == 1) ? Wk : Wv;
    unsigned short h4[4], l4[4];
#pragma unroll
    for (int i = 0; i < 4; i++) {
        float x = W[(size_t)(4 * kc + i) * HID + n];
        unsigned hb = f2bf_bits(x);
        float hf = __uint_as_float(hb << 16);
        h4[i] = (unsigned short)hb;
        l4[i] = (unsigned short)f2bf_bits(x - hf);
    }
    size_t o = ((size_t)z * HID + n) * HID + 4 * kc;
    *(ushort4*)&Wth[o] = make_ushort4(h4[0], h4[1], h4[2], h4[3]);
    *(ushort4*)&Wtl[o] = make_ushort4(l4[0], l4[1], l4[2], l4[3]);
}

// ---------------- dist -> bf16 hi/lo (padded to DROWS) ----------------
__global__ void dist_bf(const float* __restrict__ dist,
                        unsigned short* __restrict__ Dh, unsigned short* __restrict__ Dl)
{
    int e = blockIdx.x * 256 + threadIdx.x;   // DROWS*64
    if (e >= DROWS * 64) return;
    int r = e >> 6;
    float v = (r < 4095) ? dist[(size_t)e] : 0.f;
    unsigned short h, l;
    split1(v, h, l);
    Dh[e] = h; Dl[e] = l;
}

// ---------------- SCALE*agent -> bf16 hi/lo [bh][48][64] (rows 40..47 zero) ---------
__global__ void ag_bf(const float* __restrict__ Ag,
                      unsigned short* __restrict__ Gh, unsigned short* __restrict__ Gl)
{
    int e = blockIdx.x * 256 + threadIdx.x;   // 192*48*64
    if (e >= 192 * 48 * 64) return;
    int d = e & 63;
    int a = (e >> 6) % 48;
    int bh = e / (48 * 64);
    float v = (a < A_) ? SCALE_ * Ag[((size_t)bh * A_ + a) * D_ + d] : 0.f;
    unsigned short h, l;
    split1(v, h, l);
    Gh[e] = h; Gl[e] = l;
}

// ---------------- AgV^T -> bf16 hi/lo [bh][64 d][64 a] (a 40..63 zero) ----------
__global__ void avt_bf(const float* __restrict__ AgV,
                       unsigned short* __restrict__ Vh, unsigned short* __restrict__ Vl)
{
    int e = blockIdx.x * 256 + threadIdx.x;   // 192*64*64
    if (e >= 192 * 64 * 64) return;
    int a = e & 63;
    int d = (e >> 6) & 63;
    int bh = e >> 12;
    float v = (a < A_) ? AgV[((size_t)bh * A_ + a) * D_ + d] : 0.f;
    unsigned short h, l;
    split1(v, h, l);
    Vh[e] = h; Vl[e] = l;
}

// ---------------- QKV: bf16x3 MFMA GEMM (32x32x16), 128x256 tile, XCD-swizzled ----------
__global__ __launch_bounds__(512, 2) void qkv_z(
    const float* __restrict__ X,
    const unsigned short* __restrict__ Wth, const unsigned short* __restrict__ Wtl,
    const float* __restrict__ bq, const float* __restrict__ bk, const float* __restrict__ bv,
    float* __restrict__ Q, float* __restrict__ K, float* __restrict__ V)
{
    const int L   = blockIdx.x;
    const int k8  = L & 7, sl_ = L >> 3;
    const int mt  = k8 * 32 + sl_ / 9;
    const int sub = sl_ % 9;
    const int nt  = sub % 3, zz = sub / 3;
    const int m0 = mt * 128, n0 = nt * 256;

    const float* __restrict__ bias = (zz == 0) ? bq : (zz == 1) ? bk : bv;
    float* __restrict__ Out        = (zz == 0) ? Q  : (zz == 1) ? K  : V;
    const unsigned short* __restrict__ Bhg = Wth + (size_t)zz * HID * HID;
    const unsigned short* __restrict__ Blg = Wtl + (size_t)zz * HID * HID;

    __shared__ unsigned short Ah[128][40];
    __shared__ unsigned short Al[128][40];
    __shared__ unsigned short Bh[256][40];
    __shared__ unsigned short Bl[256][40];

    const int t = threadIdx.x;
    const int lane = t & 63, w = t >> 6;
    const int wm = (w & 1) * 64, wn = (w >> 1) * 64;
    const int r32 = lane & 31, kh = lane >> 5;

    const int sr = t >> 2, sca = (t & 3) * 8;
    const int sb = t >> 1, scb = (t & 1) * 16;

    f32x16 acc[2][2];
#pragma unroll
    for (int i = 0; i < 2; i++)
#pragma unroll
        for (int j = 0; j < 2; j++)
#pragma unroll
            for (int p = 0; p < 16; p++) acc[i][j][p] = 0.f;

    for (int k0 = 0; k0 < HID; k0 += 32) {
        float xv[8];
        const float* xp = X + (size_t)(m0 + sr) * HID + k0 + sca;
        float4 f0 = *(const float4*)xp;
        float4 f1 = *(const float4*)(xp + 4);
        xv[0] = f0.x; xv[1] = f0.y; xv[2] = f0.z; xv[3] = f0.w;
        xv[4] = f1.x; xv[5] = f1.y; xv[6] = f1.z; xv[7] = f1.w;
        int4 ah, al;
        split8c(xv, ah, al);
        size_t bo = (size_t)(n0 + sb) * HID + k0 + scb;
        int4 bh0 = *(const int4*)&Bhg[bo];
        int4 bh1 = *(const int4*)&Bhg[bo + 8];
        int4 bl0 = *(const int4*)&Blg[bo];
        int4 bl1 = *(const int4*)&Blg[bo + 8];

        __syncthreads();
        *(int4*)&Ah[sr][sca] = ah;
        *(int4*)&Al[sr][sca] = al;
        *(int4*)&Bh[sb][scb]     = bh0;  *(int4*)&Bh[sb][scb + 8] = bh1;
        *(int4*)&Bl[sb][scb]     = bl0;  *(int4*)&Bl[sb][scb + 8] = bl1;
        __syncthreads();

#pragma unroll
        for (int ks = 0; ks < 2; ks++) {
            const int ko = ks * 16 + kh * 8;
            short8v a_h[2], a_l[2], b_h[2], b_l[2];
#pragma unroll
            for (int i = 0; i < 2; i++) {
                a_h[i] = *(const short8v*)&Ah[wm + i * 32 + r32][ko];
                a_l[i] = *(const short8v*)&Al[wm + i * 32 + r32][ko];
                b_h[i] = *(const short8v*)&Bh[wn + i * 32 + r32][ko];
                b_l[i] = *(const short8v*)&Bl[wn + i * 32 + r32][ko];
            }
#pragma unroll
            for (int i = 0; i < 2; i++)
#pragma unroll
                for (int j = 0; j < 2; j++) {
                    acc[i][j] = __builtin_amdgcn_mfma_f32_32x32x16_bf16(a_h[i], b_h[j], acc[i][j], 0, 0, 0);
                    acc[i][j] = __builtin_amdgcn_mfma_f32_32x32x16_bf16(a_l[i], b_h[j], acc[i][j], 0, 0, 0);
                    acc[i][j] = __builtin_amdgcn_mfma_f32_32x32x16_bf16(a_h[i], b_l[j], acc[i][j], 0, 0, 0);
                }
        }
    }

    const float scl = (zz == 1) ? SCALE_ : 1.0f;
#pragma unroll
    for (int j = 0; j < 2; j++) {
        int n = n0 + wn + j * 32 + r32;
        float bj = bias[n];
        int h = n >> 6, d = n & 63;
#pragma unroll
        for (int i = 0; i < 2; i++) {
#pragma unroll
            for (int p = 0; p < 16; p++) {
                int m = m0 + wm + i * 32 + (p & 3) + 8 * (p >> 2) + 4 * kh;
                int b = m >> 11, s = m & 2047;
                Out[(((size_t)b * H_ + h) * S_ + s) * D_ + d] = (acc[i][j][p] + bj) * scl;
            }
        }
    }
}

// ---------------- agent pooling ----------------
__global__ void agent_pool(const float* __restrict__ Q, float* __restrict__ Ag)
{
    int idx = blockIdx.x * 256 + threadIdx.x;
    if (idx >= B_ * H_ * A_ * D_) return;
    int d  = idx & 63;
    int a  = (idx >> 6) % A_;
    int bh = idx / (A_ * D_);
    float src = ((float)a + 0.5f) * (2048.0f / 40.0f) - 0.5f;
    src = fminf(fmaxf(src, 0.0f), 2047.0f);
    int lo = (int)floorf(src);
    int hi = min(lo + 1, S_ - 1);
    float w = src - (float)lo;
    const float* base = Q + (size_t)bh * (S_ * D_);
    Ag[idx] = base[lo * D_ + d] * (1.0f - w) + base[hi * D_ + d] * w;
}

// ---------------- stage 1 partial (proven): pe-band in LDS ----------------
__global__ __launch_bounds__(256, 3) void stage1_part(
    const float* __restrict__ Kl, const float* __restrict__ Vl,
    const float* __restrict__ Ag, const float* __restrict__ dist,
    const float* __restrict__ mask,
    float* __restrict__ Pacc, float* __restrict__ Pm, float* __restrict__ Pl)
{
    const int q  = blockIdx.x;
    const int bh = blockIdx.y;
    const int b  = bh / H_;
    const int s0 = q * (NSUB * SUBT);
    const float* __restrict__ kb = Kl + (size_t)bh * (S_ * D_);
    const float* __restrict__ vb = Vl + (size_t)bh * (S_ * D_);

    __shared__ float ag[A_][D_];
    __shared__ float pv[103 * 68];
    __shared__ float sc[SUBT][44];
    __shared__ float pm6[6][A_];
    __shared__ float mrow[A_], lrow[A_], resc[A_];

    const int t  = threadIdx.x;
    const int sl = t >> 2, dq = t & 3;

    for (int i = t; i < A_ * D_ / 4; i += 256)
        ((float4*)ag)[i] = ((const float4*)(Ag + (size_t)bh * (A_ * D_)))[i];
    if (t < A_) { mrow[t] = -INFINITY; lrow[t] = 0.0f; }

    float4 acc[3];
#pragma unroll
    for (int ii = 0; ii < 3; ii++) acc[ii] = make_float4(0.f, 0.f, 0.f, 0.f);

    for (int st = 0; st < NSUB; st++) {
        const int sb = s0 + st * SUBT;
        const int jbase = 1984 - sb;

        __syncthreads();
        for (int i = t; i < 103 * 16; i += 256) {
            int r = i >> 4, c = i & 15;
            *(float4*)&pv[r * 68 + c * 4] = *(const float4*)&dist[(size_t)(jbase + r) * D_ + c * 4];
        }
        const int s = sb + sl;
        float4 kreg[4];
        const float* kp = kb + (size_t)s * D_ + dq * 16;
#pragma unroll
        for (int c = 0; c < 4; c++) kreg[c] = *(const float4*)(kp + 4 * c);
        float mval = mask[(size_t)b * S_ + s];
        __syncthreads();

        for (int a = 0; a < A_; a++) {
            const float* per = &pv[(a + 63 - sl) * 68 + dq * 16];
            const float* agr = &ag[a][dq * 16];
            float sum = 0.0f;
#pragma unroll
            for (int c = 0; c < 4; c++) {
                float4 p4 = *(const float4*)(per + 4 * c);
                float4 a4 = *(const float4*)(agr + 4 * c);
                float4 k4 = kreg[c];
                sum = fmaf(a4.x, k4.x + p4.x, sum);
                sum = fmaf(a4.y, k4.y + p4.y, sum);
                sum = fmaf(a4.z, k4.z + p4.z, sum);
                sum = fmaf(a4.w, k4.w + p4.w, sum);
            }
            sum += __shfl_xor(sum, 1);
            sum += __shfl_xor(sum, 2);
            if (dq == 0) sc[sl][a] = sum + mval;
        }
        __syncthreads();

        for (int i = t; i < SUBT * 16; i += 256) {
            int r = i >> 4, c = i & 15;
            *(float4*)&pv[r * 68 + c * 4] = *(const float4*)&vb[(size_t)(sb + r) * D_ + c * 4];
        }
        if (t < 240) {
            int a = t % 40, r6 = t / 40;
            float mx = -INFINITY;
            for (int i = r6; i < SUBT; i += 6) mx = fmaxf(mx, sc[i][a]);
            pm6[r6][a] = mx;
        }
        __syncthreads();
        if (t < A_) {
            float lm = pm6[0][t];
#pragma unroll
            for (int r6 = 1; r6 < 6; r6++) lm = fmaxf(lm, pm6[r6][t]);
            float mnew = fmaxf(mrow[t], lm);
            resc[t] = __expf(mrow[t] - mnew);
            mrow[t] = mnew;
        }
        __syncthreads();
        for (int i = t; i < SUBT * A_; i += 256) {
            int rr = i / 40, aa = i - rr * 40;
            sc[rr][aa] = __expf(sc[rr][aa] - mrow[aa]);
        }
        __syncthreads();
        if (t < 240) {
            int a = t % 40, r6 = t / 40;
            float sm = 0.0f;
            for (int i = r6; i < SUBT; i += 6) sm += sc[i][a];
            pm6[r6][a] = sm;
        }
        __syncthreads();
        if (t < A_) {
            float ls = pm6[0][t] + pm6[1][t] + pm6[2][t] + pm6[3][t] + pm6[4][t] + pm6[5][t];
            lrow[t] = lrow[t] * resc[t] + ls;
        }

#pragma unroll
        for (int ii = 0; ii < 3; ii++) {
            int i = t + ii * 256;
            if (i < A_ * 16) {
                int a = i >> 4, d4 = i & 15;
                float rs = resc[a];
                float4 c4 = acc[ii];
                c4.x *= rs; c4.y *= rs; c4.z *= rs; c4.w *= rs;
                for (int rr = 0; rr < SUBT; rr++) {
                    float p = sc[rr][a];
                    float4 v4 = *(const float4*)&pv[rr * 68 + d4 * 4];
                    c4.x = fmaf(p, v4.x, c4.x);
                    c4.y = fmaf(p, v4.y, c4.y);
                    c4.z = fmaf(p, v4.z, c4.z);
                    c4.w = fmaf(p, v4.w, c4.w);
                }
                acc[ii] = c4;
            }
        }
    }
    __syncthreads();
#pragma unroll
    for (int ii = 0; ii < 3; ii++) {
        int i = t + ii * 256;
        if (i < A_ * 16) {
            int a = i >> 4, d4 = i & 15;
            *(float4*)&Pacc[(((size_t)(bh * CH1 + q) * A_) + a) * D_ + d4 * 4] = acc[ii];
        }
    }
    if (t < A_) {
        Pm[(size_t)(bh * CH1 + q) * A_ + t] = mrow[t];
        Pl[(size_t)(bh * CH1 + q) * A_ + t] = lrow[t];
    }
}

// ---------------- stage 1 reduce ----------------
__global__ __launch_bounds__(256) void stage1_reduce(
    const float* __restrict__ Pacc, const float* __restrict__ Pm,
    const float* __restrict__ Pl, float* __restrict__ AgV)
{
    const int bh = blockIdx.x;
    const int t = threadIdx.x;
    __shared__ float F[CH1][A_], Linv[A_];
    if (t < A_) {
        float M = -INFINITY;
#pragma unroll
        for (int q = 0; q < CH1; q++) M = fmaxf(M, Pm[(size_t)(bh * CH1 + q) * A_ + t]);
        float L = 0.0f;
#pragma unroll
        for (int q = 0; q < CH1; q++) {
            float f = __expf(Pm[(size_t)(bh * CH1 + q) * A_ + t] - M);
            F[q][t] = f;
            L = fmaf(f, Pl[(size_t)(bh * CH1 + q) * A_ + t], L);
        }
        Linv[t] = 1.0f / L;
    }
    __syncthreads();
#pragma unroll
    for (int ii = 0; ii < 3; ii++) {
        int i = t + ii * 256;
        if (i < A_ * 16) {
            int a = i >> 4, d4 = i & 15;
            float4 s4 = make_float4(0.f, 0.f, 0.f, 0.f);
            for (int q = 0; q < CH1; q++) {
                float f = F[q][a];
                float4 p4 = *(const float4*)&Pacc[(((size_t)(bh * CH1 + q) * A_) + a) * D_ + d4 * 4];
                s4.x = fmaf(f, p4.x, s4.x);
                s4.y = fmaf(f, p4.y, s4.y);
                s4.z = fmaf(f, p4.z, s4.z);
                s4.w = fmaf(f, p4.w, s4.w);
            }
            float inv = Linv[a];
            s4.x *= inv; s4.y *= inv; s4.z *= inv; s4.w *= inv;
            *(float4*)&AgV[(size_t)bh * (A_ * D_) + a * D_ + d4 * 4] = s4;
        }
    }
}

// ---------------- stage 2: MFMA (S^T = [AG|PE]·Q^T, softmax, O = P·AgV) ----------------
// 128 s per block, 4 waves; A-operands (AG/PE/AVT) read as fragments from L2-hot bf16 tables.
__global__ __launch_bounds__(256) void stage2_mfma(
    const float* __restrict__ Qg,
    const unsigned short* __restrict__ AGh, const unsigned short* __restrict__ AGl,
    const unsigned short* __restrict__ Dh,  const unsigned short* __restrict__ Dl,
    const unsigned short* __restrict__ AVh, const unsigned short* __restrict__ AVl,
    float* __restrict__ Out)
{
    const int sbk = blockIdx.x;      // 0..15
    const int bh  = blockIdx.y;      // 0..191
    const int b = bh / H_, h = bh % H_;
    const int s0 = sbk * 128;
    const int jbase = s0 + 2008;     // dist row for (s,a): s-a+2047 -> local = sl+39-a

    __shared__ unsigned short Qh[128][72], Qlo[128][72];   // 36.9 KB
    __shared__ float scm[128][52];                          // main scores [s][a]  26.6 KB
    __shared__ float scp[128][68];                          // pe scores [s][j-16*ts] 34.8 KB
    __shared__ unsigned short PAh[128][72], PAl[128][72];  // P bf16 hi/lo  36.9 KB

    const int t = threadIdx.x;
    const int lane = t & 63, w = t >> 6;
    const int fr = lane & 15, kg = lane >> 4;

    // ---- stage Q -> bf16 hi/lo in LDS ----
    {
        const int r = t >> 1, ch = (t & 1) * 32;
        const float* qp = Qg + ((size_t)bh * S_ + s0 + r) * D_ + ch;
#pragma unroll
        for (int u = 0; u < 4; u++) {
            float xv[8];
            float4 f0 = *(const float4*)(qp + u * 8);
            float4 f1 = *(const float4*)(qp + u * 8 + 4);
            xv[0]=f0.x; xv[1]=f0.y; xv[2]=f0.z; xv[3]=f0.w;
            xv[4]=f1.x; xv[5]=f1.y; xv[6]=f1.z; xv[7]=f1.w;
            int4 hi, lo;
            split8c(xv, hi, lo);
            *(int4*)&Qh[r][ch + u * 8]  = hi;
            *(int4*)&Qlo[r][ch + u * 8] = lo;
        }
    }
    __syncthreads();

    // ---- GEMM1: per wave, s-tiles {2w, 2w+1} x (3 AG + 4 PE) col-tiles ----
#pragma unroll
    for (int tsl = 0; tsl < 2; tsl++) {
        const int ts = 2 * w + tsl;
        short8v qh[2], ql[2];
#pragma unroll
        for (int ks = 0; ks < 2; ks++) {
            qh[ks] = *(const short8v*)&Qh[ts * 16 + fr][ks * 32 + kg * 8];
            ql[ks] = *(const short8v*)&Qlo[ts * 16 + fr][ks * 32 + kg * 8];
        }
#pragma unroll
        for (int at = 0; at < 3; at++) {
            f32x4 acc = (f32x4){0.f, 0.f, 0.f, 0.f};
#pragma unroll
            for (int ks = 0; ks < 2; ks++) {
                size_t o = ((size_t)bh * 48 + at * 16 + fr) * 64 + ks * 32 + kg * 8;
                short8v chv = *(const short8v*)&AGh[o];
                short8v clv = *(const short8v*)&AGl[o];
                acc = __builtin_amdgcn_mfma_f32_16x16x32_bf16(chv, qh[ks], acc, 0, 0, 0);
                acc = __builtin_amdgcn_mfma_f32_16x16x32_bf16(clv, qh[ks], acc, 0, 0, 0);
                acc = __builtin_amdgcn_mfma_f32_16x16x32_bf16(chv, ql[ks], acc, 0, 0, 0);
            }
#pragma unroll
            for (int r = 0; r < 4; r++)
                scm[ts * 16 + fr][at * 16 + kg * 4 + r] = acc[r];
        }
#pragma unroll
        for (int o4 = 0; o4 < 4; o4++) {
            f32x4 acc = (f32x4){0.f, 0.f, 0.f, 0.f};
            const int jr = jbase + (ts + o4) * 16 + fr;
#pragma unroll
            for (int ks = 0; ks < 2; ks++) {
                size_t o = (size_t)jr * 64 + ks * 32 + kg * 8;
                short8v chv = *(const short8v*)&Dh[o];
                short8v clv = *(const short8v*)&Dl[o];
                acc = __builtin_amdgcn_mfma_f32_16x16x32_bf16(chv, qh[ks], acc, 0, 0, 0);
                acc = __builtin_amdgcn_mfma_f32_16x16x32_bf16(clv, qh[ks], acc, 0, 0, 0);
                acc = __builtin_amdgcn_mfma_f32_16x16x32_bf16(chv, ql[ks], acc, 0, 0, 0);
            }
#pragma unroll
            for (int r = 0; r < 4; r++)
                scp[ts * 16 + fr][o4 * 16 + kg * 4 + r] = acc[r];
        }
    }
    __syncthreads();

    // ---- softmax over a (40) + P split to bf16 hi/lo (threads 0..127, one s each) ----
    if (t < 128) {
        const int sl = t;
        const int base = (sl & 15) + 39;
        float val[40];
#pragma unroll
        for (int c = 0; c < 10; c++) {
            float4 m4 = *(const float4*)&scm[sl][c * 4];
            val[c*4+0] = m4.x + scp[sl][base - (c*4+0)];
            val[c*4+1] = m4.y + scp[sl][base - (c*4+1)];
            val[c*4+2] = m4.z + scp[sl][base - (c*4+2)];
            val[c*4+3] = m4.w + scp[sl][base - (c*4+3)];
        }
        float mx = -INFINITY;
#pragma unroll
        for (int a = 0; a < 40; a++) mx = fmaxf(mx, val[a]);
        float sum = 0.f;
#pragma unroll
        for (int a = 0; a < 40; a++) { val[a] = __expf(val[a] - mx); sum += val[a]; }
        float inv = 1.0f / sum;
        unsigned* ph = (unsigned*)&PAh[sl][0];
        unsigned* pl = (unsigned*)&PAl[sl][0];
#pragma unroll
        for (int a2 = 0; a2 < 20; a2++) {
            unsigned short h0, l0, h1, l1;
            split1(val[2*a2] * inv, h0, l0);
            split1(val[2*a2+1] * inv, h1, l1);
            ph[a2] = (unsigned)h0 | ((unsigned)h1 << 16);
            pl[a2] = (unsigned)l0 | ((unsigned)l1 << 16);
        }
#pragma unroll
        for (int a2 = 20; a2 < 32; a2++) { ph[a2] = 0u; pl[a2] = 0u; }
    }
    __syncthreads();

    // ---- PV: O = P(128x64pad) x AVT^T -> per wave 2 s-tiles x 4 d-tiles ----
#pragma unroll
    for (int tsl = 0; tsl < 2; tsl++) {
        const int ts = 2 * w + tsl;
        short8v ph8[2], pl8[2];
#pragma unroll
        for (int ks = 0; ks < 2; ks++) {
            ph8[ks] = *(const short8v*)&PAh[ts * 16 + fr][ks * 32 + kg * 8];
            pl8[ks] = *(const short8v*)&PAl[ts * 16 + fr][ks * 32 + kg * 8];
        }
#pragma unroll
        for (int nt = 0; nt < 4; nt++) {
            f32x4 acc = (f32x4){0.f, 0.f, 0.f, 0.f};
#pragma unroll
            for (int ks = 0; ks < 2; ks++) {
                size_t o = ((size_t)bh * 64 + nt * 16 + fr) * 64 + ks * 32 + kg * 8;
                short8v vh = *(const short8v*)&AVh[o];
                short8v vl = *(const short8v*)&AVl[o];
                acc = __builtin_amdgcn_mfma_f32_16x16x32_bf16(ph8[ks], vh, acc, 0, 0, 0);
                acc = __builtin_amdgcn_mfma_f32_16x16x32_bf16(pl8[ks], vh, acc, 0, 0, 0);
                acc = __builtin_amdgcn_mfma_f32_16x16x32_bf16(ph8[ks], vl, acc, 0, 0, 0);
            }
            const int d = nt * 16 + fr;
            float* op = Out + ((size_t)b * S_ + s0 + ts * 16 + kg * 4) * HID + h * D_ + d;
#pragma unroll
            for (int r = 0; r < 4; r++)
                op[(size_t)r * HID] = acc[r];
        }
    }
}

extern "C" void kernel_launch(void* const* d_in, const int* in_sizes, int n_in,
                              void* d_out, int out_size, void* d_ws, size_t ws_size,
                              hipStream_t stream) {
    const float* hs   = (const float*)d_in[0];
    const float* mask = (const float*)d_in[1];
    const float* Wq   = (const float*)d_in[2];
    const float* bq   = (const float*)d_in[3];
    const float* Wk   = (const float*)d_in[4];
    const float* bk   = (const float*)d_in[5];
    const float* Wv   = (const float*)d_in[6];
    const float* bv   = (const float*)d_in[7];
    const float* dist = (const float*)d_in[8];
    float* out = (float*)d_out;

    float* ws = (float*)d_ws;
    const size_t QKV = (size_t)B_ * H_ * S_ * D_;   // 25,165,824 floats each
    const size_t AG  = (size_t)B_ * H_ * A_ * D_;   // 491,520 floats
    float* Q     = ws;
    float* K     = ws + QKV;
    float* V     = ws + 2 * QKV;
    float* Agent = ws + 3 * QKV;
    float* AgV   = Agent + AG;
    float* Pacc  = AgV + AG;
    float* Pm    = Pacc + (size_t)B_ * H_ * CH1 * A_ * D_;
    float* Pl    = Pm + (size_t)B_ * H_ * CH1 * A_;
    unsigned short* Wth = (unsigned short*)(Pl + (size_t)B_ * H_ * CH1 * A_);
    unsigned short* Wtl = Wth + (size_t)3 * HID * HID;
    unsigned short* Dh  = Wtl + (size_t)3 * HID * HID;
    unsigned short* Dl  = Dh + (size_t)DROWS * 64;
    unsigned short* AGh = Dl + (size_t)DROWS * 64;
    unsigned short* AGl = AGh + (size_t)192 * 48 * 64;
    unsigned short* AVh = AGl + (size_t)192 * 48 * 64;
    unsigned short* AVl = AVh + (size_t)192 * 64 * 64;
    // total ws ~336 MB (within the known-good <=393 MB budget)

    wt_convert<<<(3 * 192 * 768 + 255) / 256, 256, 0, stream>>>(Wq, Wk, Wv, Wth, Wtl);
    dist_bf<<<(DROWS * 64 + 255) / 256, 256, 0, stream>>>(dist, Dh, Dl);
    qkv_z<<<2304, 512, 0, stream>>>(hs, Wth, Wtl, bq, bk, bv, Q, K, V);
    agent_pool<<<(B_ * H_ * A_ * D_ + 255) / 256, 256, 0, stream>>>(Q, Agent);
    ag_bf<<<(192 * 48 * 64 + 255) / 256, 256, 0, stream>>>(Agent, AGh, AGl);
    dim3 g1(CH1, B_ * H_);
    stage1_part<<<g1, 256, 0, stream>>>(K, V, Agent, dist, mask, Pacc, Pm, Pl);
    stage1_reduce<<<B_ * H_, 256, 0, stream>>>(Pacc, Pm, Pl, AgV);
    avt_bf<<<(192 * 64 * 64 + 255) / 256, 256, 0, stream>>>(AgV, AVh, AVl);
    dim3 g2(16, B_ * H_);
    stage2_mfma<<<g2, 256, 0, stream>>>(Q, AGh, AGl, Dh, Dl, AVh, AVl, out);
}

// Round 11
// 700.215 us; speedup vs baseline: 1.0561x; 1.0561x over previous
//
#include <hip/hip_runtime.h>
#include <math.h>

#define B_ 16
#define S_ 2048
#define H_ 12
#define D_ 64
#define HID 768
#define A_ 40
#define SCALE_ 0.125f
#define CH1 8          // stage1 s-chunks per (b,h)
#define SUBT 64        // s per subtile
#define NSUB 4         // subtiles per block (256 s per block)
#define DROWS 4112     // padded dist rows (4095 real + zero pad)

typedef __attribute__((ext_vector_type(8))) short short8v;    // 8 bf16 (4 VGPR)
typedef __attribute__((ext_vector_type(4))) float f32x4;
typedef __attribute__((ext_vector_type(16))) float f32x16;    // 32x32 MFMA C/D

__device__ __forceinline__ unsigned f2bf_bits(float x) {
    unsigned u = __float_as_uint(x);
    return (u + 0x7FFFu + ((u >> 16) & 1u)) >> 16;   // RTNE
}

__device__ __forceinline__ void split1(float v, unsigned short& h, unsigned short& l) {
    __bf16 bh = (__bf16)v;
    float hf = (float)bh;
    __bf16 bl = (__bf16)(v - hf);
    h = __builtin_bit_cast(unsigned short, bh);
    l = __builtin_bit_cast(unsigned short, bl);
}

// split 8 fp32 -> hi/lo bf16 via native __bf16 casts (RTNE)
__device__ __forceinline__ void split8c(const float* x, int4& hi, int4& lo) {
    unsigned h[8], l[8];
#pragma unroll
    for (int i = 0; i < 8; i++) {
        __bf16 bh = (__bf16)x[i];
        float hf = (float)bh;
        __bf16 bl = (__bf16)(x[i] - hf);
        h[i] = (unsigned)__builtin_bit_cast(unsigned short, bh);
        l[i] = (unsigned)__builtin_bit_cast(unsigned short, bl);
    }
    hi = make_int4((int)(h[0] | (h[1] << 16)), (int)(h[2] | (h[3] << 16)),
                   (int)(h[4] | (h[5] << 16)), (int)(h[6] | (h[7] << 16)));
    lo = make_int4((int)(l[0] | (l[1] << 16)), (int)(l[2] | (l[3] << 16)),
                   (int)(l[4] | (l[5] << 16)), (int)(l[6] | (l[7] << 16)));
}

// ---------------- W transpose + bf16 hi/lo split: Wt[z][n][k] ----------------
__global__ void wt_convert(const float* __restrict__ Wq, const float* __restrict__ Wk,
                           const float* __restrict__ Wv,
                           unsigned short* __restrict__ Wth, unsigned short* __restrict__ Wtl)
{
    int idx = blockIdx.x * 256 + threadIdx.x;          // 3 * 192 * 768
    if (idx >= 3 * 192 * 768) return;
    int n  = idx % 768;
    int kc = (idx / 768) % 192;
    int z  = idx / (768 * 192);
    const float* W = (z == 0) ? Wq : (z == 1) ? Wk : Wv;
    unsigned short h4[4], l4[4];
#pragma unroll
    for (int i = 0; i < 4; i++) {
        float x = W[(size_t)(4 * kc + i) * HID + n];
        unsigned hb = f2bf_bits(x);
        float hf = __uint_as_float(hb << 16);
        h4[i] = (unsigned short)hb;
        l4[i] = (unsigned short)f2bf_bits(x - hf);
    }
    size_t o = ((size_t)z * HID + n) * HID + 4 * kc;
    *(ushort4*)&Wth[o] = make_ushort4(h4[0], h4[1], h4[2], h4[3]);
    *(ushort4*)&Wtl[o] = make_ushort4(l4[0], l4[1], l4[2], l4[3]);
}

// ---------------- dist -> bf16 hi/lo (padded to DROWS) ----------------
__global__ void dist_bf(const float* __restrict__ dist,
                        unsigned short* __restrict__ Dh, unsigned short* __restrict__ Dl)
{
    int e = blockIdx.x * 256 + threadIdx.x;   // DROWS*64
    if (e >= DROWS * 64) return;
    int r = e >> 6;
    float v = (r < 4095) ? dist[(size_t)e] : 0.f;
    unsigned short h, l;
    split1(v, h, l);
    Dh[e] = h; Dl[e] = l;
}

// ---------------- SCALE*agent -> bf16 hi/lo [bh][48][64] (rows 40..47 zero) ---------
__global__ void ag_bf(const float* __restrict__ Ag,
                      unsigned short* __restrict__ Gh, unsigned short* __restrict__ Gl)
{
    int e = blockIdx.x * 256 + threadIdx.x;   // 192*48*64
    if (e >= 192 * 48 * 64) return;
    int d = e & 63;
    int a = (e >> 6) % 48;
    int bh = e / (48 * 64);
    float v = (a < A_) ? SCALE_ * Ag[((size_t)bh * A_ + a) * D_ + d] : 0.f;
    unsigned short h, l;
    split1(v, h, l);
    Gh[e] = h; Gl[e] = l;
}

// ---------------- AgV^T -> bf16 hi/lo [bh][64 d][64 a] (a 40..63 zero) ----------
__global__ void avt_bf(const float* __restrict__ AgV,
                       unsigned short* __restrict__ Vh, unsigned short* __restrict__ Vl)
{
    int e = blockIdx.x * 256 + threadIdx.x;   // 192*64*64
    if (e >= 192 * 64 * 64) return;
    int a = e & 63;
    int d = (e >> 6) & 63;
    int bh = e >> 12;
    float v = (a < A_) ? AgV[((size_t)bh * A_ + a) * D_ + d] : 0.f;
    unsigned short h, l;
    split1(v, h, l);
    Vh[e] = h; Vl[e] = l;
}

// ---------------- QKV: bf16x3 MFMA GEMM (32x32x16), 128x256 tile, XCD-swizzled ----------
__global__ __launch_bounds__(512, 2) void qkv_z(
    const float* __restrict__ X,
    const unsigned short* __restrict__ Wth, const unsigned short* __restrict__ Wtl,
    const float* __restrict__ bq, const float* __restrict__ bk, const float* __restrict__ bv,
    float* __restrict__ Q, float* __restrict__ K, float* __restrict__ V)
{
    const int L   = blockIdx.x;
    const int k8  = L & 7, sl_ = L >> 3;
    const int mt  = k8 * 32 + sl_ / 9;
    const int sub = sl_ % 9;
    const int nt  = sub % 3, zz = sub / 3;
    const int m0 = mt * 128, n0 = nt * 256;

    const float* __restrict__ bias = (zz == 0) ? bq : (zz == 1) ? bk : bv;
    float* __restrict__ Out        = (zz == 0) ? Q  : (zz == 1) ? K  : V;
    const unsigned short* __restrict__ Bhg = Wth + (size_t)zz * HID * HID;
    const unsigned short* __restrict__ Blg = Wtl + (size_t)zz * HID * HID;

    __shared__ unsigned short Ah[128][40];
    __shared__ unsigned short Al[128][40];
    __shared__ unsigned short Bh[256][40];
    __shared__ unsigned short Bl[256][40];

    const int t = threadIdx.x;
    const int lane = t & 63, w = t >> 6;
    const int wm = (w & 1) * 64, wn = (w >> 1) * 64;
    const int r32 = lane & 31, kh = lane >> 5;

    const int sr = t >> 2, sca = (t & 3) * 8;
    const int sb = t >> 1, scb = (t & 1) * 16;

    f32x16 acc[2][2];
#pragma unroll
    for (int i = 0; i < 2; i++)
#pragma unroll
        for (int j = 0; j < 2; j++)
#pragma unroll
            for (int p = 0; p < 16; p++) acc[i][j][p] = 0.f;

    for (int k0 = 0; k0 < HID; k0 += 32) {
        float xv[8];
        const float* xp = X + (size_t)(m0 + sr) * HID + k0 + sca;
        float4 f0 = *(const float4*)xp;
        float4 f1 = *(const float4*)(xp + 4);
        xv[0] = f0.x; xv[1] = f0.y; xv[2] = f0.z; xv[3] = f0.w;
        xv[4] = f1.x; xv[5] = f1.y; xv[6] = f1.z; xv[7] = f1.w;
        int4 ah, al;
        split8c(xv, ah, al);
        size_t bo = (size_t)(n0 + sb) * HID + k0 + scb;
        int4 bh0 = *(const int4*)&Bhg[bo];
        int4 bh1 = *(const int4*)&Bhg[bo + 8];
        int4 bl0 = *(const int4*)&Blg[bo];
        int4 bl1 = *(const int4*)&Blg[bo + 8];

        __syncthreads();
        *(int4*)&Ah[sr][sca] = ah;
        *(int4*)&Al[sr][sca] = al;
        *(int4*)&Bh[sb][scb]     = bh0;  *(int4*)&Bh[sb][scb + 8] = bh1;
        *(int4*)&Bl[sb][scb]     = bl0;  *(int4*)&Bl[sb][scb + 8] = bl1;
        __syncthreads();

#pragma unroll
        for (int ks = 0; ks < 2; ks++) {
            const int ko = ks * 16 + kh * 8;
            short8v a_h[2], a_l[2], b_h[2], b_l[2];
#pragma unroll
            for (int i = 0; i < 2; i++) {
                a_h[i] = *(const short8v*)&Ah[wm + i * 32 + r32][ko];
                a_l[i] = *(const short8v*)&Al[wm + i * 32 + r32][ko];
                b_h[i] = *(const short8v*)&Bh[wn + i * 32 + r32][ko];
                b_l[i] = *(const short8v*)&Bl[wn + i * 32 + r32][ko];
            }
#pragma unroll
            for (int i = 0; i < 2; i++)
#pragma unroll
                for (int j = 0; j < 2; j++) {
                    acc[i][j] = __builtin_amdgcn_mfma_f32_32x32x16_bf16(a_h[i], b_h[j], acc[i][j], 0, 0, 0);
                    acc[i][j] = __builtin_amdgcn_mfma_f32_32x32x16_bf16(a_l[i], b_h[j], acc[i][j], 0, 0, 0);
                    acc[i][j] = __builtin_amdgcn_mfma_f32_32x32x16_bf16(a_h[i], b_l[j], acc[i][j], 0, 0, 0);
                }
        }
    }

    const float scl = (zz == 1) ? SCALE_ : 1.0f;
#pragma unroll
    for (int j = 0; j < 2; j++) {
        int n = n0 + wn + j * 32 + r32;
        float bj = bias[n];
        int h = n >> 6, d = n & 63;
#pragma unroll
        for (int i = 0; i < 2; i++) {
#pragma unroll
            for (int p = 0; p < 16; p++) {
                int m = m0 + wm + i * 32 + (p & 3) + 8 * (p >> 2) + 4 * kh;
                int b = m >> 11, s = m & 2047;
                Out[(((size_t)b * H_ + h) * S_ + s) * D_ + d] = (acc[i][j][p] + bj) * scl;
            }
        }
    }
}

// ---------------- agent pooling ----------------
__global__ void agent_pool(const float* __restrict__ Q, float* __restrict__ Ag)
{
    int idx = blockIdx.x * 256 + threadIdx.x;
    if (idx >= B_ * H_ * A_ * D_) return;
    int d  = idx & 63;
    int a  = (idx >> 6) % A_;
    int bh = idx / (A_ * D_);
    float src = ((float)a + 0.5f) * (2048.0f / 40.0f) - 0.5f;
    src = fminf(fmaxf(src, 0.0f), 2047.0f);
    int lo = (int)floorf(src);
    int hi = min(lo + 1, S_ - 1);
    float w = src - (float)lo;
    const float* base = Q + (size_t)bh * (S_ * D_);
    Ag[idx] = base[lo * D_ + d] * (1.0f - w) + base[hi * D_ + d] * w;
}

// ---------------- stage 1 partial (proven): pe-band in LDS ----------------
__global__ __launch_bounds__(256, 3) void stage1_part(
    const float* __restrict__ Kl, const float* __restrict__ Vl,
    const float* __restrict__ Ag, const float* __restrict__ dist,
    const float* __restrict__ mask,
    float* __restrict__ Pacc, float* __restrict__ Pm, float* __restrict__ Pl)
{
    const int q  = blockIdx.x;
    const int bh = blockIdx.y;
    const int b  = bh / H_;
    const int s0 = q * (NSUB * SUBT);
    const float* __restrict__ kb = Kl + (size_t)bh * (S_ * D_);
    const float* __restrict__ vb = Vl + (size_t)bh * (S_ * D_);

    __shared__ float ag[A_][D_];
    __shared__ float pv[103 * 68];
    __shared__ float sc[SUBT][44];
    __shared__ float pm6[6][A_];
    __shared__ float mrow[A_], lrow[A_], resc[A_];

    const int t  = threadIdx.x;
    const int sl = t >> 2, dq = t & 3;

    for (int i = t; i < A_ * D_ / 4; i += 256)
        ((float4*)ag)[i] = ((const float4*)(Ag + (size_t)bh * (A_ * D_)))[i];
    if (t < A_) { mrow[t] = -INFINITY; lrow[t] = 0.0f; }

    float4 acc[3];
#pragma unroll
    for (int ii = 0; ii < 3; ii++) acc[ii] = make_float4(0.f, 0.f, 0.f, 0.f);

    for (int st = 0; st < NSUB; st++) {
        const int sb = s0 + st * SUBT;
        const int jbase = 1984 - sb;

        __syncthreads();
        for (int i = t; i < 103 * 16; i += 256) {
            int r = i >> 4, c = i & 15;
            *(float4*)&pv[r * 68 + c * 4] = *(const float4*)&dist[(size_t)(jbase + r) * D_ + c * 4];
        }
        const int s = sb + sl;
        float4 kreg[4];
        const float* kp = kb + (size_t)s * D_ + dq * 16;
#pragma unroll
        for (int c = 0; c < 4; c++) kreg[c] = *(const float4*)(kp + 4 * c);
        float mval = mask[(size_t)b * S_ + s];
        __syncthreads();

        for (int a = 0; a < A_; a++) {
            const float* per = &pv[(a + 63 - sl) * 68 + dq * 16];
            const float* agr = &ag[a][dq * 16];
            float sum = 0.0f;
#pragma unroll
            for (int c = 0; c < 4; c++) {
                float4 p4 = *(const float4*)(per + 4 * c);
                float4 a4 = *(const float4*)(agr + 4 * c);
                float4 k4 = kreg[c];
                sum = fmaf(a4.x, k4.x + p4.x, sum);
                sum = fmaf(a4.y, k4.y + p4.y, sum);
                sum = fmaf(a4.z, k4.z + p4.z, sum);
                sum = fmaf(a4.w, k4.w + p4.w, sum);
            }
            sum += __shfl_xor(sum, 1);
            sum += __shfl_xor(sum, 2);
            if (dq == 0) sc[sl][a] = sum + mval;
        }
        __syncthreads();

        for (int i = t; i < SUBT * 16; i += 256) {
            int r = i >> 4, c = i & 15;
            *(float4*)&pv[r * 68 + c * 4] = *(const float4*)&vb[(size_t)(sb + r) * D_ + c * 4];
        }
        if (t < 240) {
            int a = t % 40, r6 = t / 40;
            float mx = -INFINITY;
            for (int i = r6; i < SUBT; i += 6) mx = fmaxf(mx, sc[i][a]);
            pm6[r6][a] = mx;
        }
        __syncthreads();
        if (t < A_) {
            float lm = pm6[0][t];
#pragma unroll
            for (int r6 = 1; r6 < 6; r6++) lm = fmaxf(lm, pm6[r6][t]);
            float mnew = fmaxf(mrow[t], lm);
            resc[t] = __expf(mrow[t] - mnew);
            mrow[t] = mnew;
        }
        __syncthreads();
        for (int i = t; i < SUBT * A_; i += 256) {
            int rr = i / 40, aa = i - rr * 40;
            sc[rr][aa] = __expf(sc[rr][aa] - mrow[aa]);
        }
        __syncthreads();
        if (t < 240) {
            int a = t % 40, r6 = t / 40;
            float sm = 0.0f;
            for (int i = r6; i < SUBT; i += 6) sm += sc[i][a];
            pm6[r6][a] = sm;
        }
        __syncthreads();
        if (t < A_) {
            float ls = pm6[0][t] + pm6[1][t] + pm6[2][t] + pm6[3][t] + pm6[4][t] + pm6[5][t];
            lrow[t] = lrow[t] * resc[t] + ls;
        }

#pragma unroll
        for (int ii = 0; ii < 3; ii++) {
            int i = t + ii * 256;
            if (i < A_ * 16) {
                int a = i >> 4, d4 = i & 15;
                float rs = resc[a];
                float4 c4 = acc[ii];
                c4.x *= rs; c4.y *= rs; c4.z *= rs; c4.w *= rs;
                for (int rr = 0; rr < SUBT; rr++) {
                    float p = sc[rr][a];
                    float4 v4 = *(const float4*)&pv[rr * 68 + d4 * 4];
                    c4.x = fmaf(p, v4.x, c4.x);
                    c4.y = fmaf(p, v4.y, c4.y);
                    c4.z = fmaf(p, v4.z, c4.z);
                    c4.w = fmaf(p, v4.w, c4.w);
                }
                acc[ii] = c4;
            }
        }
    }
    __syncthreads();
#pragma unroll
    for (int ii = 0; ii < 3; ii++) {
        int i = t + ii * 256;
        if (i < A_ * 16) {
            int a = i >> 4, d4 = i & 15;
            *(float4*)&Pacc[(((size_t)(bh * CH1 + q) * A_) + a) * D_ + d4 * 4] = acc[ii];
        }
    }
    if (t < A_) {
        Pm[(size_t)(bh * CH1 + q) * A_ + t] = mrow[t];
        Pl[(size_t)(bh * CH1 + q) * A_ + t] = lrow[t];
    }
}

// ---------------- stage 1 reduce ----------------
__global__ __launch_bounds__(256) void stage1_reduce(
    const float* __restrict__ Pacc, const float* __restrict__ Pm,
    const float* __restrict__ Pl, float* __restrict__ AgV)
{
    const int bh = blockIdx.x;
    const int t = threadIdx.x;
    __shared__ float F[CH1][A_], Linv[A_];
    if (t < A_) {
        float M = -INFINITY;
#pragma unroll
        for (int q = 0; q < CH1; q++) M = fmaxf(M, Pm[(size_t)(bh * CH1 + q) * A_ + t]);
        float L = 0.0f;
#pragma unroll
        for (int q = 0; q < CH1; q++) {
            float f = __expf(Pm[(size_t)(bh * CH1 + q) * A_ + t] - M);
            F[q][t] = f;
            L = fmaf(f, Pl[(size_t)(bh * CH1 + q) * A_ + t], L);
        }
        Linv[t] = 1.0f / L;
    }
    __syncthreads();
#pragma unroll
    for (int ii = 0; ii < 3; ii++) {
        int i = t + ii * 256;
        if (i < A_ * 16) {
            int a = i >> 4, d4 = i & 15;
            float4 s4 = make_float4(0.f, 0.f, 0.f, 0.f);
            for (int q = 0; q < CH1; q++) {
                float f = F[q][a];
                float4 p4 = *(const float4*)&Pacc[(((size_t)(bh * CH1 + q) * A_) + a) * D_ + d4 * 4];
                s4.x = fmaf(f, p4.x, s4.x);
                s4.y = fmaf(f, p4.y, s4.y);
                s4.z = fmaf(f, p4.z, s4.z);
                s4.w = fmaf(f, p4.w, s4.w);
            }
            float inv = Linv[a];
            s4.x *= inv; s4.y *= inv; s4.z *= inv; s4.w *= inv;
            *(float4*)&AgV[(size_t)bh * (A_ * D_) + a * D_ + d4 * 4] = s4;
        }
    }
}

// ---------------- stage 2 MFMA v2: 64 s per block, 4 waves, no Q staging ----------------
// Per wave: s-tile ts=w. Scores S^T via mfma(AG|PE, Q); softmax per-s; O via mfma(P, AVT).
__global__ __launch_bounds__(256, 3) void stage2_mfma(
    const float* __restrict__ Qg,
    const unsigned short* __restrict__ AGh, const unsigned short* __restrict__ AGl,
    const unsigned short* __restrict__ Dh,  const unsigned short* __restrict__ Dl,
    const unsigned short* __restrict__ AVh, const unsigned short* __restrict__ AVl,
    float* __restrict__ Out)
{
    const int sbk = blockIdx.x;      // 0..31
    const int bh  = blockIdx.y;      // 0..191
    const int b = bh / H_, h = bh % H_;
    const int s0 = sbk * 64;
    const int jbase = s0 + 2008;     // dist row: s-a+2047 -> local = (s-s0)+39-a

    __shared__ float scm[64][52];                          // main scores [s][a]  13.3 KB
    __shared__ float scp[64][68];                          // pe scores [s][rel j] 17.4 KB
    __shared__ unsigned short PAh[64][72], PAl[64][72];    // P bf16 hi/lo  18.4 KB

    const int t = threadIdx.x;
    const int lane = t & 63, ts = t >> 6;   // ts = wave's s-tile
    const int fr = lane & 15, kg = lane >> 4;

    // ---- per-lane Q fragment: direct global load + in-register split ----
    short8v qh[2], ql[2];
    {
        const float* qp = Qg + ((size_t)bh * S_ + s0 + ts * 16 + fr) * D_;
#pragma unroll
        for (int ks = 0; ks < 2; ks++) {
            float xv[8];
            float4 f0 = *(const float4*)(qp + ks * 32 + kg * 8);
            float4 f1 = *(const float4*)(qp + ks * 32 + kg * 8 + 4);
            xv[0]=f0.x; xv[1]=f0.y; xv[2]=f0.z; xv[3]=f0.w;
            xv[4]=f1.x; xv[5]=f1.y; xv[6]=f1.z; xv[7]=f1.w;
            int4 hi, lo;
            split8c(xv, hi, lo);
            qh[ks] = __builtin_bit_cast(short8v, hi);
            ql[ks] = __builtin_bit_cast(short8v, lo);
        }
    }

    // ---- GEMM1a: AG scores (3 col-tiles of a) ----
#pragma unroll
    for (int at = 0; at < 3; at++) {
        f32x4 acc = (f32x4){0.f, 0.f, 0.f, 0.f};
#pragma unroll
        for (int ks = 0; ks < 2; ks++) {
            size_t o = ((size_t)bh * 48 + at * 16 + fr) * 64 + ks * 32 + kg * 8;
            short8v chv = *(const short8v*)&AGh[o];
            short8v clv = *(const short8v*)&AGl[o];
            acc = __builtin_amdgcn_mfma_f32_16x16x32_bf16(chv, qh[ks], acc, 0, 0, 0);
            acc = __builtin_amdgcn_mfma_f32_16x16x32_bf16(clv, qh[ks], acc, 0, 0, 0);
            acc = __builtin_amdgcn_mfma_f32_16x16x32_bf16(chv, ql[ks], acc, 0, 0, 0);
        }
        *(f32x4*)&scm[ts * 16 + fr][at * 16 + kg * 4] = acc;
    }
    // ---- GEMM1b: PE scores (4 band tiles) ----
#pragma unroll
    for (int o4 = 0; o4 < 4; o4++) {
        f32x4 acc = (f32x4){0.f, 0.f, 0.f, 0.f};
        const int jr = jbase + (ts + o4) * 16 + fr;
#pragma unroll
        for (int ks = 0; ks < 2; ks++) {
            size_t o = (size_t)jr * 64 + ks * 32 + kg * 8;
            short8v chv = *(const short8v*)&Dh[o];
            short8v clv = *(const short8v*)&Dl[o];
            acc = __builtin_amdgcn_mfma_f32_16x16x32_bf16(chv, qh[ks], acc, 0, 0, 0);
            acc = __builtin_amdgcn_mfma_f32_16x16x32_bf16(clv, qh[ks], acc, 0, 0, 0);
            acc = __builtin_amdgcn_mfma_f32_16x16x32_bf16(chv, ql[ks], acc, 0, 0, 0);
        }
        *(f32x4*)&scp[ts * 16 + fr][o4 * 16 + kg * 4] = acc;
    }
    __syncthreads();

    // ---- softmax over a (40) + P split to bf16 hi/lo (threads 0..63, one s each) ----
    if (t < 64) {
        const int sl = t;
        const int base = (sl & 15) + 39;
        float val[40];
#pragma unroll
        for (int c = 0; c < 10; c++) {
            float4 m4 = *(const float4*)&scm[sl][c * 4];
            val[c*4+0] = m4.x + scp[sl][base - (c*4+0)];
            val[c*4+1] = m4.y + scp[sl][base - (c*4+1)];
            val[c*4+2] = m4.z + scp[sl][base - (c*4+2)];
            val[c*4+3] = m4.w + scp[sl][base - (c*4+3)];
        }
        float mx = -INFINITY;
#pragma unroll
        for (int a = 0; a < 40; a++) mx = fmaxf(mx, val[a]);
        float sum = 0.f;
#pragma unroll
        for (int a = 0; a < 40; a++) { val[a] = __expf(val[a] - mx); sum += val[a]; }
        float inv = 1.0f / sum;
        unsigned* ph = (unsigned*)&PAh[sl][0];
        unsigned* pl = (unsigned*)&PAl[sl][0];
#pragma unroll
        for (int a2 = 0; a2 < 20; a2++) {
            unsigned short h0, l0, h1, l1;
            split1(val[2*a2] * inv, h0, l0);
            split1(val[2*a2+1] * inv, h1, l1);
            ph[a2] = (unsigned)h0 | ((unsigned)h1 << 16);
            pl[a2] = (unsigned)l0 | ((unsigned)l1 << 16);
        }
#pragma unroll
        for (int a2 = 20; a2 < 32; a2++) { ph[a2] = 0u; pl[a2] = 0u; }
    }
    __syncthreads();

    // ---- PV: O = P x AgV (B-operand = AVT rows d, fragments from global) ----
    short8v ph8[2], pl8[2];
#pragma unroll
    for (int ks = 0; ks < 2; ks++) {
        ph8[ks] = *(const short8v*)&PAh[ts * 16 + fr][ks * 32 + kg * 8];
        pl8[ks] = *(const short8v*)&PAl[ts * 16 + fr][ks * 32 + kg * 8];
    }
#pragma unroll
    for (int nt = 0; nt < 4; nt++) {
        f32x4 acc = (f32x4){0.f, 0.f, 0.f, 0.f};
#pragma unroll
        for (int ks = 0; ks < 2; ks++) {
            size_t o = ((size_t)bh * 64 + nt * 16 + fr) * 64 + ks * 32 + kg * 8;
            short8v vh = *(const short8v*)&AVh[o];
            short8v vl = *(const short8v*)&AVl[o];
            acc = __builtin_amdgcn_mfma_f32_16x16x32_bf16(ph8[ks], vh, acc, 0, 0, 0);
            acc = __builtin_amdgcn_mfma_f32_16x16x32_bf16(pl8[ks], vh, acc, 0, 0, 0);
            acc = __builtin_amdgcn_mfma_f32_16x16x32_bf16(ph8[ks], vl, acc, 0, 0, 0);
        }
        const int d = nt * 16 + fr;
        float* op = Out + ((size_t)b * S_ + s0 + ts * 16 + kg * 4) * HID + h * D_ + d;
#pragma unroll
        for (int r = 0; r < 4; r++)
            op[(size_t)r * HID] = acc[r];
    }
}

extern "C" void kernel_launch(void* const* d_in, const int* in_sizes, int n_in,
                              void* d_out, int out_size, void* d_ws, size_t ws_size,
                              hipStream_t stream) {
    const float* hs   = (const float*)d_in[0];
    const float* mask = (const float*)d_in[1];
    const float* Wq   = (const float*)d_in[2];
    const float* bq   = (const float*)d_in[3];
    const float* Wk   = (const float*)d_in[4];
    const float* bk   = (const float*)d_in[5];
    const float* Wv   = (const float*)d_in[6];
    const float* bv   = (const float*)d_in[7];
    const float* dist = (const float*)d_in[8];
    float* out = (float*)d_out;

    float* ws = (float*)d_ws;
    const size_t QKV = (size_t)B_ * H_ * S_ * D_;   // 25,165,824 floats each
    const size_t AG  = (size_t)B_ * H_ * A_ * D_;   // 491,520 floats
    float* Q     = ws;
    float* K     = ws + QKV;
    float* V     = ws + 2 * QKV;
    float* Agent = ws + 3 * QKV;
    float* AgV   = Agent + AG;
    float* Pacc  = AgV + AG;
    float* Pm    = Pacc + (size_t)B_ * H_ * CH1 * A_ * D_;
    float* Pl    = Pm + (size_t)B_ * H_ * CH1 * A_;
    unsigned short* Wth = (unsigned short*)(Pl + (size_t)B_ * H_ * CH1 * A_);
    unsigned short* Wtl = Wth + (size_t)3 * HID * HID;
    unsigned short* Dh  = Wtl + (size_t)3 * HID * HID;
    unsigned short* Dl  = Dh + (size_t)DROWS * 64;
    unsigned short* AGh = Dl + (size_t)DROWS * 64;
    unsigned short* AGl = AGh + (size_t)192 * 48 * 64;
    unsigned short* AVh = AGl + (size_t)192 * 48 * 64;
    unsigned short* AVl = AVh + (size_t)192 * 64 * 64;
    // total ws ~336 MB (within the known-good budget)

    wt_convert<<<(3 * 192 * 768 + 255) / 256, 256, 0, stream>>>(Wq, Wk, Wv, Wth, Wtl);
    dist_bf<<<(DROWS * 64 + 255) / 256, 256, 0, stream>>>(dist, Dh, Dl);
    qkv_z<<<2304, 512, 0, stream>>>(hs, Wth, Wtl, bq, bk, bv, Q, K, V);
    agent_pool<<<(B_ * H_ * A_ * D_ + 255) / 256, 256, 0, stream>>>(Q, Agent);
    ag_bf<<<(192 * 48 * 64 + 255) / 256, 256, 0, stream>>>(Agent, AGh, AGl);
    dim3 g1(CH1, B_ * H_);
    stage1_part<<<g1, 256, 0, stream>>>(K, V, Agent, dist, mask, Pacc, Pm, Pl);
    stage1_reduce<<<B_ * H_, 256, 0, stream>>>(Pacc, Pm, Pl, AgV);
    avt_bf<<<(192 * 64 * 64 + 255) / 256, 256, 0, stream>>>(AgV, AVh, AVl);
    dim3 g2(32, B_ * H_);
    stage2_mfma<<<g2, 256, 0, stream>>>(Q, AGh, AGl, Dh, Dl, AVh, AVl, out);
}

// Round 12
// 654.364 us; speedup vs baseline: 1.1301x; 1.0701x over previous
//
#include <hip/hip_runtime.h>
#include <math.h>

#define B_ 16
#define S_ 2048
#define H_ 12
#define D_ 64
#define HID 768
#define A_ 40
#define SCALE_ 0.125f
#define CH1 8          // stage1 s-chunks per (b,h)
#define SUBT 64        // s per subtile
#define NSUB 4         // subtiles per block (256 s per block)

typedef __attribute__((ext_vector_type(8))) short short8v;    // 8 bf16 (4 VGPR)
typedef __attribute__((ext_vector_type(4))) float f32x4;
typedef __attribute__((ext_vector_type(16))) float f32x16;    // 32x32 MFMA C/D

__device__ __forceinline__ unsigned f2bf_bits(float x) {
    unsigned u = __float_as_uint(x);
    return (u + 0x7FFFu + ((u >> 16) & 1u)) >> 16;   // RTNE
}

__device__ __forceinline__ void split1(float v, unsigned short& h, unsigned short& l) {
    __bf16 bh = (__bf16)v;
    float hf = (float)bh;
    __bf16 bl = (__bf16)(v - hf);
    h = __builtin_bit_cast(unsigned short, bh);
    l = __builtin_bit_cast(unsigned short, bl);
}

// split 8 fp32 -> hi/lo bf16 via native __bf16 casts (RTNE)
__device__ __forceinline__ void split8c(const float* x, int4& hi, int4& lo) {
    unsigned h[8], l[8];
#pragma unroll
    for (int i = 0; i < 8; i++) {
        __bf16 bh = (__bf16)x[i];
        float hf = (float)bh;
        __bf16 bl = (__bf16)(x[i] - hf);
        h[i] = (unsigned)__builtin_bit_cast(unsigned short, bh);
        l[i] = (unsigned)__builtin_bit_cast(unsigned short, bl);
    }
    hi = make_int4((int)(h[0] | (h[1] << 16)), (int)(h[2] | (h[3] << 16)),
                   (int)(h[4] | (h[5] << 16)), (int)(h[6] | (h[7] << 16)));
    lo = make_int4((int)(l[0] | (l[1] << 16)), (int)(l[2] | (l[3] << 16)),
                   (int)(l[4] | (l[5] << 16)), (int)(l[6] | (l[7] << 16)));
}

// ---------------- W transpose + bf16 hi/lo split: Wt[z][n][k] ----------------
__global__ void wt_convert(const float* __restrict__ Wq, const float* __restrict__ Wk,
                           const float* __restrict__ Wv,
                           unsigned short* __restrict__ Wth, unsigned short* __restrict__ Wtl)
{
    int idx = blockIdx.x * 256 + threadIdx.x;          // 3 * 192 * 768
    if (idx >= 3 * 192 * 768) return;
    int n  = idx % 768;
    int kc = (idx / 768) % 192;
    int z  = idx / (768 * 192);
    const float* W = (z == 0) ? Wq : (z == 1) ? Wk : Wv;
    unsigned short h4[4], l4[4];
#pragma unroll
    for (int i = 0; i < 4; i++) {
        float x = W[(size_t)(4 * kc + i) * HID + n];
        unsigned hb = f2bf_bits(x);
        float hf = __uint_as_float(hb << 16);
        h4[i] = (unsigned short)hb;
        l4[i] = (unsigned short)f2bf_bits(x - hf);
    }
    size_t o = ((size_t)z * HID + n) * HID + 4 * kc;
    *(ushort4*)&Wth[o] = make_ushort4(h4[0], h4[1], h4[2], h4[3]);
    *(ushort4*)&Wtl[o] = make_ushort4(l4[0], l4[1], l4[2], l4[3]);
}

// ------- dist -> FRAGMENT-MAJOR bf16 hi/lo tiles: DF[u][ks][lane][8], u tile rows 8+16u --
__global__ void dist_frag(const float* __restrict__ dist,
                          unsigned short* __restrict__ DFh, unsigned short* __restrict__ DFl)
{
    int g = blockIdx.x * 256 + threadIdx.x;   // 256 * 2 * 64
    if (g >= 256 * 2 * 64) return;
    int lane = g & 63;
    int ks = (g >> 6) & 1;
    int u  = g >> 7;
    int row = 8 + u * 16 + (lane & 15);
    int col = ks * 32 + ((lane >> 4) << 3);
    float xv[8];
#pragma unroll
    for (int j = 0; j < 8; j++)
        xv[j] = (row < 4095) ? dist[(size_t)row * D_ + col + j] : 0.f;
    int4 hi, lo;
    split8c(xv, hi, lo);
    *(int4*)&DFh[(size_t)g * 8] = hi;
    *(int4*)&DFl[(size_t)g * 8] = lo;
}

// ------- SCALE*agent -> fragment-major: AGF[bh][at<3][ks][lane][8] (a>=40 zero) ---------
__global__ void ag_frag(const float* __restrict__ Ag,
                        unsigned short* __restrict__ Gh, unsigned short* __restrict__ Gl)
{
    int g = blockIdx.x * 256 + threadIdx.x;   // 192*3*2*64
    if (g >= 192 * 3 * 2 * 64) return;
    int lane = g & 63;
    int r = g >> 6;
    int ks = r & 1; r >>= 1;
    int at = r % 3;
    int bh = r / 3;
    int a = at * 16 + (lane & 15);
    int col = ks * 32 + ((lane >> 4) << 3);
    float xv[8];
#pragma unroll
    for (int j = 0; j < 8; j++)
        xv[j] = (a < A_) ? SCALE_ * Ag[((size_t)bh * A_ + a) * D_ + col + j] : 0.f;
    int4 hi, lo;
    split8c(xv, hi, lo);
    *(int4*)&Gh[(size_t)g * 8] = hi;
    *(int4*)&Gl[(size_t)g * 8] = lo;
}

// ------- AgV^T -> fragment-major: AVF[bh][nt<4][ks][lane][8] rows=d, cols=a (a>=40 zero) -
__global__ void avt_frag(const float* __restrict__ AgV,
                         unsigned short* __restrict__ Vh, unsigned short* __restrict__ Vl)
{
    int g = blockIdx.x * 256 + threadIdx.x;   // 192*4*2*64
    if (g >= 192 * 4 * 2 * 64) return;
    int lane = g & 63;
    int r = g >> 6;
    int ks = r & 1; r >>= 1;
    int nt = r & 3;
    int bh = r >> 2;
    int d = nt * 16 + (lane & 15);
    int a0 = ks * 32 + ((lane >> 4) << 3);
    float xv[8];
#pragma unroll
    for (int j = 0; j < 8; j++) {
        int a = a0 + j;
        xv[j] = (a < A_) ? AgV[((size_t)bh * A_ + a) * D_ + d] : 0.f;
    }
    int4 hi, lo;
    split8c(xv, hi, lo);
    *(int4*)&Vh[(size_t)g * 8] = hi;
    *(int4*)&Vl[(size_t)g * 8] = lo;
}

// ---------------- QKV: bf16x3 MFMA GEMM (32x32x16), 128x256 tile, XCD-swizzled ----------
__global__ __launch_bounds__(512, 2) void qkv_z(
    const float* __restrict__ X,
    const unsigned short* __restrict__ Wth, const unsigned short* __restrict__ Wtl,
    const float* __restrict__ bq, const float* __restrict__ bk, const float* __restrict__ bv,
    float* __restrict__ Q, float* __restrict__ K, float* __restrict__ V)
{
    const int L   = blockIdx.x;
    const int k8  = L & 7, sl_ = L >> 3;
    const int mt  = k8 * 32 + sl_ / 9;
    const int sub = sl_ % 9;
    const int nt  = sub % 3, zz = sub / 3;
    const int m0 = mt * 128, n0 = nt * 256;

    const float* __restrict__ bias = (zz == 0) ? bq : (zz == 1) ? bk : bv;
    float* __restrict__ Out        = (zz == 0) ? Q  : (zz == 1) ? K  : V;
    const unsigned short* __restrict__ Bhg = Wth + (size_t)zz * HID * HID;
    const unsigned short* __restrict__ Blg = Wtl + (size_t)zz * HID * HID;

    __shared__ unsigned short Ah[128][40];
    __shared__ unsigned short Al[128][40];
    __shared__ unsigned short Bh[256][40];
    __shared__ unsigned short Bl[256][40];

    const int t = threadIdx.x;
    const int lane = t & 63, w = t >> 6;
    const int wm = (w & 1) * 64, wn = (w >> 1) * 64;
    const int r32 = lane & 31, kh = lane >> 5;

    const int sr = t >> 2, sca = (t & 3) * 8;
    const int sb = t >> 1, scb = (t & 1) * 16;

    f32x16 acc[2][2];
#pragma unroll
    for (int i = 0; i < 2; i++)
#pragma unroll
        for (int j = 0; j < 2; j++)
#pragma unroll
            for (int p = 0; p < 16; p++) acc[i][j][p] = 0.f;

    for (int k0 = 0; k0 < HID; k0 += 32) {
        float xv[8];
        const float* xp = X + (size_t)(m0 + sr) * HID + k0 + sca;
        float4 f0 = *(const float4*)xp;
        float4 f1 = *(const float4*)(xp + 4);
        xv[0] = f0.x; xv[1] = f0.y; xv[2] = f0.z; xv[3] = f0.w;
        xv[4] = f1.x; xv[5] = f1.y; xv[6] = f1.z; xv[7] = f1.w;
        int4 ah, al;
        split8c(xv, ah, al);
        size_t bo = (size_t)(n0 + sb) * HID + k0 + scb;
        int4 bh0 = *(const int4*)&Bhg[bo];
        int4 bh1 = *(const int4*)&Bhg[bo + 8];
        int4 bl0 = *(const int4*)&Blg[bo];
        int4 bl1 = *(const int4*)&Blg[bo + 8];

        __syncthreads();
        *(int4*)&Ah[sr][sca] = ah;
        *(int4*)&Al[sr][sca] = al;
        *(int4*)&Bh[sb][scb]     = bh0;  *(int4*)&Bh[sb][scb + 8] = bh1;
        *(int4*)&Bl[sb][scb]     = bl0;  *(int4*)&Bl[sb][scb + 8] = bl1;
        __syncthreads();

#pragma unroll
        for (int ks = 0; ks < 2; ks++) {
            const int ko = ks * 16 + kh * 8;
            short8v a_h[2], a_l[2], b_h[2], b_l[2];
#pragma unroll
            for (int i = 0; i < 2; i++) {
                a_h[i] = *(const short8v*)&Ah[wm + i * 32 + r32][ko];
                a_l[i] = *(const short8v*)&Al[wm + i * 32 + r32][ko];
                b_h[i] = *(const short8v*)&Bh[wn + i * 32 + r32][ko];
                b_l[i] = *(const short8v*)&Bl[wn + i * 32 + r32][ko];
            }
#pragma unroll
            for (int i = 0; i < 2; i++)
#pragma unroll
                for (int j = 0; j < 2; j++) {
                    acc[i][j] = __builtin_amdgcn_mfma_f32_32x32x16_bf16(a_h[i], b_h[j], acc[i][j], 0, 0, 0);
                    acc[i][j] = __builtin_amdgcn_mfma_f32_32x32x16_bf16(a_l[i], b_h[j], acc[i][j], 0, 0, 0);
                    acc[i][j] = __builtin_amdgcn_mfma_f32_32x32x16_bf16(a_h[i], b_l[j], acc[i][j], 0, 0, 0);
                }
        }
    }

    const float scl = (zz == 1) ? SCALE_ : 1.0f;
#pragma unroll
    for (int j = 0; j < 2; j++) {
        int n = n0 + wn + j * 32 + r32;
        float bj = bias[n];
        int h = n >> 6, d = n & 63;
#pragma unroll
        for (int i = 0; i < 2; i++) {
#pragma unroll
            for (int p = 0; p < 16; p++) {
                int m = m0 + wm + i * 32 + (p & 3) + 8 * (p >> 2) + 4 * kh;
                int b = m >> 11, s = m & 2047;
                Out[(((size_t)b * H_ + h) * S_ + s) * D_ + d] = (acc[i][j][p] + bj) * scl;
            }
        }
    }
}

// ---------------- agent pooling ----------------
__global__ void agent_pool(const float* __restrict__ Q, float* __restrict__ Ag)
{
    int idx = blockIdx.x * 256 + threadIdx.x;
    if (idx >= B_ * H_ * A_ * D_) return;
    int d  = idx & 63;
    int a  = (idx >> 6) % A_;
    int bh = idx / (A_ * D_);
    float src = ((float)a + 0.5f) * (2048.0f / 40.0f) - 0.5f;
    src = fminf(fmaxf(src, 0.0f), 2047.0f);
    int lo = (int)floorf(src);
    int hi = min(lo + 1, S_ - 1);
    float w = src - (float)lo;
    const float* base = Q + (size_t)bh * (S_ * D_);
    Ag[idx] = base[lo * D_ + d] * (1.0f - w) + base[hi * D_ + d] * w;
}

// ---------------- stage 1 partial (proven): pe-band in LDS ----------------
__global__ __launch_bounds__(256, 3) void stage1_part(
    const float* __restrict__ Kl, const float* __restrict__ Vl,
    const float* __restrict__ Ag, const float* __restrict__ dist,
    const float* __restrict__ mask,
    float* __restrict__ Pacc, float* __restrict__ Pm, float* __restrict__ Pl)
{
    const int q  = blockIdx.x;
    const int bh = blockIdx.y;
    const int b  = bh / H_;
    const int s0 = q * (NSUB * SUBT);
    const float* __restrict__ kb = Kl + (size_t)bh * (S_ * D_);
    const float* __restrict__ vb = Vl + (size_t)bh * (S_ * D_);

    __shared__ float ag[A_][D_];
    __shared__ float pv[103 * 68];
    __shared__ float sc[SUBT][44];
    __shared__ float pm6[6][A_];
    __shared__ float mrow[A_], lrow[A_], resc[A_];

    const int t  = threadIdx.x;
    const int sl = t >> 2, dq = t & 3;

    for (int i = t; i < A_ * D_ / 4; i += 256)
        ((float4*)ag)[i] = ((const float4*)(Ag + (size_t)bh * (A_ * D_)))[i];
    if (t < A_) { mrow[t] = -INFINITY; lrow[t] = 0.0f; }

    float4 acc[3];
#pragma unroll
    for (int ii = 0; ii < 3; ii++) acc[ii] = make_float4(0.f, 0.f, 0.f, 0.f);

    for (int st = 0; st < NSUB; st++) {
        const int sb = s0 + st * SUBT;
        const int jbase = 1984 - sb;

        __syncthreads();
        for (int i = t; i < 103 * 16; i += 256) {
            int r = i >> 4, c = i & 15;
            *(float4*)&pv[r * 68 + c * 4] = *(const float4*)&dist[(size_t)(jbase + r) * D_ + c * 4];
        }
        const int s = sb + sl;
        float4 kreg[4];
        const float* kp = kb + (size_t)s * D_ + dq * 16;
#pragma unroll
        for (int c = 0; c < 4; c++) kreg[c] = *(const float4*)(kp + 4 * c);
        float mval = mask[(size_t)b * S_ + s];
        __syncthreads();

        for (int a = 0; a < A_; a++) {
            const float* per = &pv[(a + 63 - sl) * 68 + dq * 16];
            const float* agr = &ag[a][dq * 16];
            float sum = 0.0f;
#pragma unroll
            for (int c = 0; c < 4; c++) {
                float4 p4 = *(const float4*)(per + 4 * c);
                float4 a4 = *(const float4*)(agr + 4 * c);
                float4 k4 = kreg[c];
                sum = fmaf(a4.x, k4.x + p4.x, sum);
                sum = fmaf(a4.y, k4.y + p4.y, sum);
                sum = fmaf(a4.z, k4.z + p4.z, sum);
                sum = fmaf(a4.w, k4.w + p4.w, sum);
            }
            sum += __shfl_xor(sum, 1);
            sum += __shfl_xor(sum, 2);
            if (dq == 0) sc[sl][a] = sum + mval;
        }
        __syncthreads();

        for (int i = t; i < SUBT * 16; i += 256) {
            int r = i >> 4, c = i & 15;
            *(float4*)&pv[r * 68 + c * 4] = *(const float4*)&vb[(size_t)(sb + r) * D_ + c * 4];
        }
        if (t < 240) {
            int a = t % 40, r6 = t / 40;
            float mx = -INFINITY;
            for (int i = r6; i < SUBT; i += 6) mx = fmaxf(mx, sc[i][a]);
            pm6[r6][a] = mx;
        }
        __syncthreads();
        if (t < A_) {
            float lm = pm6[0][t];
#pragma unroll
            for (int r6 = 1; r6 < 6; r6++) lm = fmaxf(lm, pm6[r6][t]);
            float mnew = fmaxf(mrow[t], lm);
            resc[t] = __expf(mrow[t] - mnew);
            mrow[t] = mnew;
        }
        __syncthreads();
        for (int i = t; i < SUBT * A_; i += 256) {
            int rr = i / 40, aa = i - rr * 40;
            sc[rr][aa] = __expf(sc[rr][aa] - mrow[aa]);
        }
        __syncthreads();
        if (t < 240) {
            int a = t % 40, r6 = t / 40;
            float sm = 0.0f;
            for (int i = r6; i < SUBT; i += 6) sm += sc[i][a];
            pm6[r6][a] = sm;
        }
        __syncthreads();
        if (t < A_) {
            float ls = pm6[0][t] + pm6[1][t] + pm6[2][t] + pm6[3][t] + pm6[4][t] + pm6[5][t];
            lrow[t] = lrow[t] * resc[t] + ls;
        }

#pragma unroll
        for (int ii = 0; ii < 3; ii++) {
            int i = t + ii * 256;
            if (i < A_ * 16) {
                int a = i >> 4, d4 = i & 15;
                float rs = resc[a];
                float4 c4 = acc[ii];
                c4.x *= rs; c4.y *= rs; c4.z *= rs; c4.w *= rs;
                for (int rr = 0; rr < SUBT; rr++) {
                    float p = sc[rr][a];
                    float4 v4 = *(const float4*)&pv[rr * 68 + d4 * 4];
                    c4.x = fmaf(p, v4.x, c4.x);
                    c4.y = fmaf(p, v4.y, c4.y);
                    c4.z = fmaf(p, v4.z, c4.z);
                    c4.w = fmaf(p, v4.w, c4.w);
                }
                acc[ii] = c4;
            }
        }
    }
    __syncthreads();
#pragma unroll
    for (int ii = 0; ii < 3; ii++) {
        int i = t + ii * 256;
        if (i < A_ * 16) {
            int a = i >> 4, d4 = i & 15;
            *(float4*)&Pacc[(((size_t)(bh * CH1 + q) * A_) + a) * D_ + d4 * 4] = acc[ii];
        }
    }
    if (t < A_) {
        Pm[(size_t)(bh * CH1 + q) * A_ + t] = mrow[t];
        Pl[(size_t)(bh * CH1 + q) * A_ + t] = lrow[t];
    }
}

// ---------------- stage 1 reduce ----------------
__global__ __launch_bounds__(256) void stage1_reduce(
    const float* __restrict__ Pacc, const float* __restrict__ Pm,
    const float* __restrict__ Pl, float* __restrict__ AgV)
{
    const int bh = blockIdx.x;
    const int t = threadIdx.x;
    __shared__ float F[CH1][A_], Linv[A_];
    if (t < A_) {
        float M = -INFINITY;
#pragma unroll
        for (int q = 0; q < CH1; q++) M = fmaxf(M, Pm[(size_t)(bh * CH1 + q) * A_ + t]);
        float L = 0.0f;
#pragma unroll
        for (int q = 0; q < CH1; q++) {
            float f = __expf(Pm[(size_t)(bh * CH1 + q) * A_ + t] - M);
            F[q][t] = f;
            L = fmaf(f, Pl[(size_t)(bh * CH1 + q) * A_ + t], L);
        }
        Linv[t] = 1.0f / L;
    }
    __syncthreads();
#pragma unroll
    for (int ii = 0; ii < 3; ii++) {
        int i = t + ii * 256;
        if (i < A_ * 16) {
            int a = i >> 4, d4 = i & 15;
            float4 s4 = make_float4(0.f, 0.f, 0.f, 0.f);
            for (int q = 0; q < CH1; q++) {
                float f = F[q][a];
                float4 p4 = *(const float4*)&Pacc[(((size_t)(bh * CH1 + q) * A_) + a) * D_ + d4 * 4];
                s4.x = fmaf(f, p4.x, s4.x);
                s4.y = fmaf(f, p4.y, s4.y);
                s4.z = fmaf(f, p4.z, s4.z);
                s4.w = fmaf(f, p4.w, s4.w);
            }
            float inv = Linv[a];
            s4.x *= inv; s4.y *= inv; s4.z *= inv; s4.w *= inv;
            *(float4*)&AgV[(size_t)bh * (A_ * D_) + a * D_ + d4 * 4] = s4;
        }
    }
}

// ------- stage 2 MFMA v3: fragment-major operands, Q via LDS reshuffle, 64 s/block ------
__global__ __launch_bounds__(256, 2) void stage2_mfma(
    const float* __restrict__ Qg,
    const unsigned short* __restrict__ AGFh, const unsigned short* __restrict__ AGFl,
    const unsigned short* __restrict__ DFh,  const unsigned short* __restrict__ DFl,
    const unsigned short* __restrict__ AVFh, const unsigned short* __restrict__ AVFl,
    float* __restrict__ Out)
{
    const int sbk = blockIdx.x;      // 0..31
    const int bh  = blockIdx.y;      // 0..191
    const int b = bh / H_, h = bh % H_;
    const int s0 = sbk * 64;
    const int base_u = 4 * sbk + 125;   // D tile index: rows 8+16u; j = jbase+(ts+o4)*16+fr

    __shared__ unsigned short Qfh[8 * 64 * 8], Qfl[8 * 64 * 8];   // [ts*2+ks][lane][8] 16 KB
    __shared__ float scm[64][52];                                  // 13.3 KB
    __shared__ float scp[64][68];                                  // 17.4 KB
    __shared__ unsigned short PAh[64][72], PAl[64][72];            // 18.4 KB

    const int t = threadIdx.x;
    const int lane = t & 63, ts = t >> 6;
    const int fr = lane & 15, kg = lane >> 4;

    // ---- Q stage: coalesced 64x64 f32 -> in-reg split -> fragment-major LDS ----
    {
        const int r = t >> 2, c0 = (t & 3) * 16;
        const float* qp = Qg + ((size_t)bh * S_ + s0 + r) * D_ + c0;
        float xa[8], xb[8];
        float4 f0 = *(const float4*)(qp);
        float4 f1 = *(const float4*)(qp + 4);
        float4 f2 = *(const float4*)(qp + 8);
        float4 f3 = *(const float4*)(qp + 12);
        xa[0]=f0.x; xa[1]=f0.y; xa[2]=f0.z; xa[3]=f0.w;
        xa[4]=f1.x; xa[5]=f1.y; xa[6]=f1.z; xa[7]=f1.w;
        xb[0]=f2.x; xb[1]=f2.y; xb[2]=f2.z; xb[3]=f2.w;
        xb[4]=f3.x; xb[5]=f3.y; xb[6]=f3.z; xb[7]=f3.w;
        int4 h0, l0, h1, l1;
        split8c(xa, h0, l0);
        split8c(xb, h1, l1);
        const int tsr = r >> 4, frr = r & 15;
        const int c8a = (t & 3) * 2, c8b = c8a + 1;
        const int oa = ((tsr * 2 + (c8a >> 2)) * 64 + (((c8a & 3) << 4) | frr)) * 8;
        const int ob = ((tsr * 2 + (c8b >> 2)) * 64 + (((c8b & 3) << 4) | frr)) * 8;
        *(int4*)&Qfh[oa] = h0;  *(int4*)&Qfl[oa] = l0;
        *(int4*)&Qfh[ob] = h1;  *(int4*)&Qfl[ob] = l1;
    }
    __syncthreads();

    short8v qh[2], ql[2];
#pragma unroll
    for (int ks = 0; ks < 2; ks++) {
        qh[ks] = *(const short8v*)&Qfh[((ts * 2 + ks) * 64 + lane) * 8];
        ql[ks] = *(const short8v*)&Qfl[((ts * 2 + ks) * 64 + lane) * 8];
    }

    // ---- GEMM1a: AG scores (contiguous 1KB wave loads) ----
#pragma unroll
    for (int at = 0; at < 3; at++) {
        f32x4 acc = (f32x4){0.f, 0.f, 0.f, 0.f};
#pragma unroll
        for (int ks = 0; ks < 2; ks++) {
            size_t o = ((((size_t)bh * 3 + at) * 2 + ks) * 64 + lane) * 8;
            short8v chv = *(const short8v*)&AGFh[o];
            short8v clv = *(const short8v*)&AGFl[o];
            acc = __builtin_amdgcn_mfma_f32_16x16x32_bf16(chv, qh[ks], acc, 0, 0, 0);
            acc = __builtin_amdgcn_mfma_f32_16x16x32_bf16(clv, qh[ks], acc, 0, 0, 0);
            acc = __builtin_amdgcn_mfma_f32_16x16x32_bf16(chv, ql[ks], acc, 0, 0, 0);
        }
        *(f32x4*)&scm[ts * 16 + fr][at * 16 + kg * 4] = acc;
    }
    // ---- GEMM1b: PE scores (fragment-major D tiles) ----
#pragma unroll
    for (int o4 = 0; o4 < 4; o4++) {
        f32x4 acc = (f32x4){0.f, 0.f, 0.f, 0.f};
        const int u = base_u + ts + o4;
#pragma unroll
        for (int ks = 0; ks < 2; ks++) {
            size_t o = (((size_t)u * 2 + ks) * 64 + lane) * 8;
            short8v chv = *(const short8v*)&DFh[o];
            short8v clv = *(const short8v*)&DFl[o];
            acc = __builtin_amdgcn_mfma_f32_16x16x32_bf16(chv, qh[ks], acc, 0, 0, 0);
            acc = __builtin_amdgcn_mfma_f32_16x16x32_bf16(clv, qh[ks], acc, 0, 0, 0);
            acc = __builtin_amdgcn_mfma_f32_16x16x32_bf16(chv, ql[ks], acc, 0, 0, 0);
        }
        *(f32x4*)&scp[ts * 16 + fr][o4 * 16 + kg * 4] = acc;
    }
    __syncthreads();

    // ---- softmax over a (all 256 threads: 4 per s-row, 10 a's each) ----
    {
        const int r = t >> 2, dq = t & 3;
        const int base = (r & 15) + 39;
        float val[10];
#pragma unroll
        for (int i = 0; i < 10; i++) {
            int a = dq * 10 + i;
            val[i] = scm[r][a] + scp[r][base - a];
        }
        float mx = -INFINITY;
#pragma unroll
        for (int i = 0; i < 10; i++) mx = fmaxf(mx, val[i]);
        mx = fmaxf(mx, __shfl_xor(mx, 1));
        mx = fmaxf(mx, __shfl_xor(mx, 2));
        float sum = 0.f;
#pragma unroll
        for (int i = 0; i < 10; i++) { val[i] = __expf(val[i] - mx); sum += val[i]; }
        sum += __shfl_xor(sum, 1);
        sum += __shfl_xor(sum, 2);
        float inv = 1.0f / sum;
        unsigned* ph = (unsigned*)&PAh[r][0];
        unsigned* pl = (unsigned*)&PAl[r][0];
#pragma unroll
        for (int i = 0; i < 5; i++) {
            unsigned short h0, l0, h1, l1;
            split1(val[2 * i] * inv, h0, l0);
            split1(val[2 * i + 1] * inv, h1, l1);
            ph[dq * 5 + i] = (unsigned)h0 | ((unsigned)h1 << 16);
            pl[dq * 5 + i] = (unsigned)l0 | ((unsigned)l1 << 16);
        }
#pragma unroll
        for (int i = 0; i < 3; i++) { ph[20 + dq * 3 + i] = 0u; pl[20 + dq * 3 + i] = 0u; }
    }
    __syncthreads();

    // ---- PV: O = P x AgV (B = fragment-major AVT) ----
    short8v ph8[2], pl8[2];
#pragma unroll
    for (int ks = 0; ks < 2; ks++) {
        ph8[ks] = *(const short8v*)&PAh[ts * 16 + fr][ks * 32 + kg * 8];
        pl8[ks] = *(const short8v*)&PAl[ts * 16 + fr][ks * 32 + kg * 8];
    }
#pragma unroll
    for (int nt = 0; nt < 4; nt++) {
        f32x4 acc = (f32x4){0.f, 0.f, 0.f, 0.f};
#pragma unroll
        for (int ks = 0; ks < 2; ks++) {
            size_t o = ((((size_t)bh * 4 + nt) * 2 + ks) * 64 + lane) * 8;
            short8v vh = *(const short8v*)&AVFh[o];
            short8v vl = *(const short8v*)&AVFl[o];
            acc = __builtin_amdgcn_mfma_f32_16x16x32_bf16(ph8[ks], vh, acc, 0, 0, 0);
            acc = __builtin_amdgcn_mfma_f32_16x16x32_bf16(pl8[ks], vh, acc, 0, 0, 0);
            acc = __builtin_amdgcn_mfma_f32_16x16x32_bf16(ph8[ks], vl, acc, 0, 0, 0);
        }
        const int d = nt * 16 + fr;
        float* op = Out + ((size_t)b * S_ + s0 + ts * 16 + kg * 4) * HID + h * D_ + d;
#pragma unroll
        for (int r = 0; r < 4; r++)
            op[(size_t)r * HID] = acc[r];
    }
}

extern "C" void kernel_launch(void* const* d_in, const int* in_sizes, int n_in,
                              void* d_out, int out_size, void* d_ws, size_t ws_size,
                              hipStream_t stream) {
    const float* hs   = (const float*)d_in[0];
    const float* mask = (const float*)d_in[1];
    const float* Wq   = (const float*)d_in[2];
    const float* bq   = (const float*)d_in[3];
    const float* Wk   = (const float*)d_in[4];
    const float* bk   = (const float*)d_in[5];
    const float* Wv   = (const float*)d_in[6];
    const float* bv   = (const float*)d_in[7];
    const float* dist = (const float*)d_in[8];
    float* out = (float*)d_out;

    float* ws = (float*)d_ws;
    const size_t QKV = (size_t)B_ * H_ * S_ * D_;   // 25,165,824 floats each
    const size_t AG  = (size_t)B_ * H_ * A_ * D_;   // 491,520 floats
    float* Q     = ws;
    float* K     = ws + QKV;
    float* V     = ws + 2 * QKV;
    float* Agent = ws + 3 * QKV;
    float* AgV   = Agent + AG;
    float* Pacc  = AgV + AG;
    float* Pm    = Pacc + (size_t)B_ * H_ * CH1 * A_ * D_;
    float* Pl    = Pm + (size_t)B_ * H_ * CH1 * A_;
    unsigned short* Wth = (unsigned short*)(Pl + (size_t)B_ * H_ * CH1 * A_);
    unsigned short* Wtl = Wth + (size_t)3 * HID * HID;
    unsigned short* DFh = Wtl + (size_t)3 * HID * HID;      // 256*2*64*8 = 262,144
    unsigned short* DFl = DFh + (size_t)262144;
    unsigned short* AGFh = DFl + (size_t)262144;            // 192*3*2*64*8 = 589,824
    unsigned short* AGFl = AGFh + (size_t)589824;
    unsigned short* AVFh = AGFl + (size_t)589824;           // 192*4*2*64*8 = 786,432
    unsigned short* AVFl = AVFh + (size_t)786432;
    // total ws ~337 MB (within known-good <=393 MB budget)

    wt_convert<<<(3 * 192 * 768 + 255) / 256, 256, 0, stream>>>(Wq, Wk, Wv, Wth, Wtl);
    dist_frag<<<(256 * 2 * 64 + 255) / 256, 256, 0, stream>>>(dist, DFh, DFl);
    qkv_z<<<2304, 512, 0, stream>>>(hs, Wth, Wtl, bq, bk, bv, Q, K, V);
    agent_pool<<<(B_ * H_ * A_ * D_ + 255) / 256, 256, 0, stream>>>(Q, Agent);
    ag_frag<<<(192 * 3 * 2 * 64 + 255) / 256, 256, 0, stream>>>(Agent, AGFh, AGFl);
    dim3 g1(CH1, B_ * H_);
    stage1_part<<<g1, 256, 0, stream>>>(K, V, Agent, dist, mask, Pacc, Pm, Pl);
    stage1_reduce<<<B_ * H_, 256, 0, stream>>>(Pacc, Pm, Pl, AgV);
    avt_frag<<<(192 * 4 * 2 * 64 + 255) / 256, 256, 0, stream>>>(AgV, AVFh, AVFl);
    dim3 g2(32, B_ * H_);
    stage2_mfma<<<g2, 256, 0, stream>>>(Q, AGFh, AGFl, DFh, DFl, AVFh, AVFl, out);
}

// Round 13
// 578.544 us; speedup vs baseline: 1.2782x; 1.1311x over previous
//
#include <hip/hip_runtime.h>
#include <math.h>

#define B_ 16
#define S_ 2048
#define H_ 12
#define D_ 64
#define HID 768
#define A_ 40
#define SCALE_ 0.125f
#define CH1 8          // stage1 s-chunks per (b,h)
#define SUBT 64        // s per subtile
#define NSUB 4         // subtiles per block (256 s per block)

typedef __attribute__((ext_vector_type(8))) short short8v;    // 8 bf16 (4 VGPR)
typedef __attribute__((ext_vector_type(4))) float f32x4;
typedef __attribute__((ext_vector_type(16))) float f32x16;    // 32x32 MFMA C/D

__device__ __forceinline__ unsigned f2bf_bits(float x) {
    unsigned u = __float_as_uint(x);
    return (u + 0x7FFFu + ((u >> 16) & 1u)) >> 16;   // RTNE
}

__device__ __forceinline__ void split1(float v, unsigned short& h, unsigned short& l) {
    __bf16 bh = (__bf16)v;
    float hf = (float)bh;
    __bf16 bl = (__bf16)(v - hf);
    h = __builtin_bit_cast(unsigned short, bh);
    l = __builtin_bit_cast(unsigned short, bl);
}

// split 8 fp32 -> hi/lo bf16 via native __bf16 casts (RTNE)
__device__ __forceinline__ void split8c(const float* x, int4& hi, int4& lo) {
    unsigned h[8], l[8];
#pragma unroll
    for (int i = 0; i < 8; i++) {
        __bf16 bh = (__bf16)x[i];
        float hf = (float)bh;
        __bf16 bl = (__bf16)(x[i] - hf);
        h[i] = (unsigned)__builtin_bit_cast(unsigned short, bh);
        l[i] = (unsigned)__builtin_bit_cast(unsigned short, bl);
    }
    hi = make_int4((int)(h[0] | (h[1] << 16)), (int)(h[2] | (h[3] << 16)),
                   (int)(h[4] | (h[5] << 16)), (int)(h[6] | (h[7] << 16)));
    lo = make_int4((int)(l[0] | (l[1] << 16)), (int)(l[2] | (l[3] << 16)),
                   (int)(l[4] | (l[5] << 16)), (int)(l[6] | (l[7] << 16)));
}

// ---------------- W transpose + bf16 hi/lo split: Wt[z][n][k] ----------------
__global__ void wt_convert(const float* __restrict__ Wq, const float* __restrict__ Wk,
                           const float* __restrict__ Wv,
                           unsigned short* __restrict__ Wth, unsigned short* __restrict__ Wtl)
{
    int idx = blockIdx.x * 256 + threadIdx.x;          // 3 * 192 * 768
    if (idx >= 3 * 192 * 768) return;
    int n  = idx % 768;
    int kc = (idx / 768) % 192;
    int z  = idx / (768 * 192);
    const float* W = (z == 0) ? Wq : (z == 1) ? Wk : Wv;
    unsigned short h4[4], l4[4];
#pragma unroll
    for (int i = 0; i < 4; i++) {
        float x = W[(size_t)(4 * kc + i) * HID + n];
        unsigned hb = f2bf_bits(x);
        float hf = __uint_as_float(hb << 16);
        h4[i] = (unsigned short)hb;
        l4[i] = (unsigned short)f2bf_bits(x - hf);
    }
    size_t o = ((size_t)z * HID + n) * HID + 4 * kc;
    *(ushort4*)&Wth[o] = make_ushort4(h4[0], h4[1], h4[2], h4[3]);
    *(ushort4*)&Wtl[o] = make_ushort4(l4[0], l4[1], l4[2], l4[3]);
}

// ------- dist -> frag-major tiles rows 8+16u (stage2 lattice), u<256 --------
__global__ void dist_frag(const float* __restrict__ dist,
                          unsigned short* __restrict__ DFh, unsigned short* __restrict__ DFl)
{
    int g = blockIdx.x * 256 + threadIdx.x;   // 256 * 2 * 64
    if (g >= 256 * 2 * 64) return;
    int lane = g & 63;
    int ks = (g >> 6) & 1;
    int u  = g >> 7;
    int row = 8 + u * 16 + (lane & 15);
    int col = ks * 32 + ((lane >> 4) << 3);
    float xv[8];
#pragma unroll
    for (int j = 0; j < 8; j++)
        xv[j] = (row < 4095) ? dist[(size_t)row * D_ + col + j] : 0.f;
    int4 hi, lo;
    split8c(xv, hi, lo);
    *(int4*)&DFh[(size_t)g * 8] = hi;
    *(int4*)&DFl[(size_t)g * 8] = lo;
}

// ------- dist -> frag-major tiles rows 16u (stage1 lattice), u<131 ----------
__global__ void dist_frag0(const float* __restrict__ dist,
                           unsigned short* __restrict__ Dh, unsigned short* __restrict__ Dl)
{
    int g = blockIdx.x * 256 + threadIdx.x;   // 131 * 2 * 64
    if (g >= 131 * 2 * 64) return;
    int lane = g & 63;
    int ks = (g >> 6) & 1;
    int u  = g >> 7;
    int row = u * 16 + (lane & 15);           // <= 2095, all real
    int col = ks * 32 + ((lane >> 4) << 3);
    float xv[8];
#pragma unroll
    for (int j = 0; j < 8; j++) xv[j] = dist[(size_t)row * D_ + col + j];
    int4 hi, lo;
    split8c(xv, hi, lo);
    *(int4*)&Dh[(size_t)g * 8] = hi;
    *(int4*)&Dl[(size_t)g * 8] = lo;
}

// ------- scale*agent -> fragment-major: [bh][at<3][ks][lane][8] (a>=40 zero) ---------
__global__ void ag_frag(const float* __restrict__ Ag,
                        unsigned short* __restrict__ Gh, unsigned short* __restrict__ Gl,
                        float scale)
{
    int g = blockIdx.x * 256 + threadIdx.x;   // 192*3*2*64
    if (g >= 192 * 3 * 2 * 64) return;
    int lane = g & 63;
    int r = g >> 6;
    int ks = r & 1; r >>= 1;
    int at = r % 3;
    int bh = r / 3;
    int a = at * 16 + (lane & 15);
    int col = ks * 32 + ((lane >> 4) << 3);
    float xv[8];
#pragma unroll
    for (int j = 0; j < 8; j++)
        xv[j] = (a < A_) ? scale * Ag[((size_t)bh * A_ + a) * D_ + col + j] : 0.f;
    int4 hi, lo;
    split8c(xv, hi, lo);
    *(int4*)&Gh[(size_t)g * 8] = hi;
    *(int4*)&Gl[(size_t)g * 8] = lo;
}

// ------- AgV^T -> fragment-major: [bh][nt<4][ks][lane][8] rows=d, cols=a ----------
__global__ void avt_frag(const float* __restrict__ AgV,
                         unsigned short* __restrict__ Vh, unsigned short* __restrict__ Vl)
{
    int g = blockIdx.x * 256 + threadIdx.x;   // 192*4*2*64
    if (g >= 192 * 4 * 2 * 64) return;
    int lane = g & 63;
    int r = g >> 6;
    int ks = r & 1; r >>= 1;
    int nt = r & 3;
    int bh = r >> 2;
    int d = nt * 16 + (lane & 15);
    int a0 = ks * 32 + ((lane >> 4) << 3);
    float xv[8];
#pragma unroll
    for (int j = 0; j < 8; j++) {
        int a = a0 + j;
        xv[j] = (a < A_) ? AgV[((size_t)bh * A_ + a) * D_ + d] : 0.f;
    }
    int4 hi, lo;
    split8c(xv, hi, lo);
    *(int4*)&Vh[(size_t)g * 8] = hi;
    *(int4*)&Vl[(size_t)g * 8] = lo;
}

// ---------------- QKV: bf16x3 MFMA GEMM (32x32x16), 128x256 tile, XCD-swizzled ----------
__global__ __launch_bounds__(512, 2) void qkv_z(
    const float* __restrict__ X,
    const unsigned short* __restrict__ Wth, const unsigned short* __restrict__ Wtl,
    const float* __restrict__ bq, const float* __restrict__ bk, const float* __restrict__ bv,
    float* __restrict__ Q, float* __restrict__ K, float* __restrict__ V)
{
    const int L   = blockIdx.x;
    const int k8  = L & 7, sl_ = L >> 3;
    const int mt  = k8 * 32 + sl_ / 9;
    const int sub = sl_ % 9;
    const int nt  = sub % 3, zz = sub / 3;
    const int m0 = mt * 128, n0 = nt * 256;

    const float* __restrict__ bias = (zz == 0) ? bq : (zz == 1) ? bk : bv;
    float* __restrict__ Out        = (zz == 0) ? Q  : (zz == 1) ? K  : V;
    const unsigned short* __restrict__ Bhg = Wth + (size_t)zz * HID * HID;
    const unsigned short* __restrict__ Blg = Wtl + (size_t)zz * HID * HID;

    __shared__ unsigned short Ah[128][40];
    __shared__ unsigned short Al[128][40];
    __shared__ unsigned short Bh[256][40];
    __shared__ unsigned short Bl[256][40];

    const int t = threadIdx.x;
    const int lane = t & 63, w = t >> 6;
    const int wm = (w & 1) * 64, wn = (w >> 1) * 64;
    const int r32 = lane & 31, kh = lane >> 5;

    const int sr = t >> 2, sca = (t & 3) * 8;
    const int sb = t >> 1, scb = (t & 1) * 16;

    f32x16 acc[2][2];
#pragma unroll
    for (int i = 0; i < 2; i++)
#pragma unroll
        for (int j = 0; j < 2; j++)
#pragma unroll
            for (int p = 0; p < 16; p++) acc[i][j][p] = 0.f;

    for (int k0 = 0; k0 < HID; k0 += 32) {
        float xv[8];
        const float* xp = X + (size_t)(m0 + sr) * HID + k0 + sca;
        float4 f0 = *(const float4*)xp;
        float4 f1 = *(const float4*)(xp + 4);
        xv[0] = f0.x; xv[1] = f0.y; xv[2] = f0.z; xv[3] = f0.w;
        xv[4] = f1.x; xv[5] = f1.y; xv[6] = f1.z; xv[7] = f1.w;
        int4 ah, al;
        split8c(xv, ah, al);
        size_t bo = (size_t)(n0 + sb) * HID + k0 + scb;
        int4 bh0 = *(const int4*)&Bhg[bo];
        int4 bh1 = *(const int4*)&Bhg[bo + 8];
        int4 bl0 = *(const int4*)&Blg[bo];
        int4 bl1 = *(const int4*)&Blg[bo + 8];

        __syncthreads();
        *(int4*)&Ah[sr][sca] = ah;
        *(int4*)&Al[sr][sca] = al;
        *(int4*)&Bh[sb][scb]     = bh0;  *(int4*)&Bh[sb][scb + 8] = bh1;
        *(int4*)&Bl[sb][scb]     = bl0;  *(int4*)&Bl[sb][scb + 8] = bl1;
        __syncthreads();

#pragma unroll
        for (int ks = 0; ks < 2; ks++) {
            const int ko = ks * 16 + kh * 8;
            short8v a_h[2], a_l[2], b_h[2], b_l[2];
#pragma unroll
            for (int i = 0; i < 2; i++) {
                a_h[i] = *(const short8v*)&Ah[wm + i * 32 + r32][ko];
                a_l[i] = *(const short8v*)&Al[wm + i * 32 + r32][ko];
                b_h[i] = *(const short8v*)&Bh[wn + i * 32 + r32][ko];
                b_l[i] = *(const short8v*)&Bl[wn + i * 32 + r32][ko];
            }
#pragma unroll
            for (int i = 0; i < 2; i++)
#pragma unroll
                for (int j = 0; j < 2; j++) {
                    acc[i][j] = __builtin_amdgcn_mfma_f32_32x32x16_bf16(a_h[i], b_h[j], acc[i][j], 0, 0, 0);
                    acc[i][j] = __builtin_amdgcn_mfma_f32_32x32x16_bf16(a_l[i], b_h[j], acc[i][j], 0, 0, 0);
                    acc[i][j] = __builtin_amdgcn_mfma_f32_32x32x16_bf16(a_h[i], b_l[j], acc[i][j], 0, 0, 0);
                }
        }
    }

    const float scl = (zz == 1) ? SCALE_ : 1.0f;
#pragma unroll
    for (int j = 0; j < 2; j++) {
        int n = n0 + wn + j * 32 + r32;
        float bj = bias[n];
        int h = n >> 6, d = n & 63;
#pragma unroll
        for (int i = 0; i < 2; i++) {
#pragma unroll
            for (int p = 0; p < 16; p++) {
                int m = m0 + wm + i * 32 + (p & 3) + 8 * (p >> 2) + 4 * kh;
                int b = m >> 11, s = m & 2047;
                Out[(((size_t)b * H_ + h) * S_ + s) * D_ + d] = (acc[i][j][p] + bj) * scl;
            }
        }
    }
}

// ---------------- agent pooling ----------------
__global__ void agent_pool(const float* __restrict__ Q, float* __restrict__ Ag)
{
    int idx = blockIdx.x * 256 + threadIdx.x;
    if (idx >= B_ * H_ * A_ * D_) return;
    int d  = idx & 63;
    int a  = (idx >> 6) % A_;
    int bh = idx / (A_ * D_);
    float src = ((float)a + 0.5f) * (2048.0f / 40.0f) - 0.5f;
    src = fminf(fmaxf(src, 0.0f), 2047.0f);
    int lo = (int)floorf(src);
    int hi = min(lo + 1, S_ - 1);
    float w = src - (float)lo;
    const float* base = Q + (size_t)bh * (S_ * D_);
    Ag[idx] = base[lo * D_ + d] * (1.0f - w) + base[hi * D_ + d] * w;
}

// ---------------- stage 1 MFMA: flash over s-chunks, all GEMM phases on matrix cores ----
// Per block (chunk q, bh): 4 subtiles of 64 s. Scores = mfma(AG1, K) + banded mfma(AG1, D0).
// Proven softmax split-reductions; P->bf16 frags; PV = mfma(P, V^T). Partials as before.
__global__ __launch_bounds__(256, 2) void stage1_mfma(
    const float* __restrict__ Kl, const float* __restrict__ Vl,
    const unsigned short* __restrict__ AG1h, const unsigned short* __restrict__ AG1l,
    const unsigned short* __restrict__ D0h,  const unsigned short* __restrict__ D0l,
    const float* __restrict__ mask,
    float* __restrict__ Pacc, float* __restrict__ Pm, float* __restrict__ Pl)
{
    const int q  = blockIdx.x;       // 0..7
    const int bh = blockIdx.y;       // 0..191
    const int b  = bh / H_;
    const int s0 = q * (NSUB * SUBT);
    const float* __restrict__ kb = Kl + (size_t)bh * (S_ * D_);
    const float* __restrict__ vb = Vl + (size_t)bh * (S_ * D_);

    __shared__ unsigned short KFh[4096], KFl[4096];   // K frags / P frags (overlaid) 16 KB
    __shared__ unsigned short VTh[4096], VTl[4096];   // V^T frags 16 KB
    __shared__ float sc[SUBT][52];                    // scores [s][a] 13.3 KB
    __shared__ float scp[112][52];                    // bias [jrel][a] 23.3 KB
    __shared__ float pm6[6][A_];
    __shared__ float mrow[A_], lrow[A_], resc[A_], mrw[SUBT];

    const int t = threadIdx.x;
    const int lane = t & 63, w = t >> 6;
    const int fr = lane & 15, kg = lane >> 4;

    if (t < A_) { mrow[t] = -INFINITY; lrow[t] = 0.0f; }

    f32x4 acc3[3];
#pragma unroll
    for (int at = 0; at < 3; at++) acc3[at] = (f32x4){0.f, 0.f, 0.f, 0.f};

    for (int st = 0; st < NSUB; st++) {
        const int sb = s0 + st * SUBT;
        const int u0 = (1984 - sb) >> 4;      // D0 tile base (jbase = 1984-sb, 16-aligned)

        __syncthreads();   // prior subtile's PV reads done; init visible on st=0

        // ---- stage K -> fragment-major (verified staging pattern) ----
        {
            const int r = t >> 2, c0 = (t & 3) * 16;
            const float* kp = kb + (size_t)(sb + r) * D_ + c0;
            float xa[8], xb[8];
            float4 f0 = *(const float4*)(kp);
            float4 f1 = *(const float4*)(kp + 4);
            float4 f2 = *(const float4*)(kp + 8);
            float4 f3 = *(const float4*)(kp + 12);
            xa[0]=f0.x; xa[1]=f0.y; xa[2]=f0.z; xa[3]=f0.w;
            xa[4]=f1.x; xa[5]=f1.y; xa[6]=f1.z; xa[7]=f1.w;
            xb[0]=f2.x; xb[1]=f2.y; xb[2]=f2.z; xb[3]=f2.w;
            xb[4]=f3.x; xb[5]=f3.y; xb[6]=f3.z; xb[7]=f3.w;
            int4 h0, l0, h1, l1;
            split8c(xa, h0, l0);
            split8c(xb, h1, l1);
            const int tsr = r >> 4, frr = r & 15;
            const int c8a = (t & 3) * 2, c8b = c8a + 1;
            const int oa = ((tsr * 2 + (c8a >> 2)) * 64 + (((c8a & 3) << 4) | frr)) * 8;
            const int ob = ((tsr * 2 + (c8b >> 2)) * 64 + (((c8b & 3) << 4) | frr)) * 8;
            *(int4*)&KFh[oa] = h0;  *(int4*)&KFl[oa] = l0;
            *(int4*)&KFh[ob] = h1;  *(int4*)&KFl[ob] = l1;
        }
        // ---- stage V^T -> fragment-major (scalar transpose writes) ----
        {
            const int r = t >> 2, c0 = (t & 3) * 16;
            const float* vp = vb + (size_t)(sb + r) * D_ + c0;
            float vv[16];
            float4 g0 = *(const float4*)(vp);
            float4 g1 = *(const float4*)(vp + 4);
            float4 g2 = *(const float4*)(vp + 8);
            float4 g3 = *(const float4*)(vp + 12);
            vv[0]=g0.x; vv[1]=g0.y; vv[2]=g0.z; vv[3]=g0.w;
            vv[4]=g1.x; vv[5]=g1.y; vv[6]=g1.z; vv[7]=g1.w;
            vv[8]=g2.x; vv[9]=g2.y; vv[10]=g2.z; vv[11]=g2.w;
            vv[12]=g3.x; vv[13]=g3.y; vv[14]=g3.z; vv[15]=g3.w;
            const int ks2 = r >> 5, kgp = (r & 31) >> 3, e = r & 7;
#pragma unroll
            for (int jj = 0; jj < 16; jj++) {
                int d = c0 + jj;
                int off = (((d >> 4) * 2 + ks2) * 64 + kgp * 16 + (d & 15)) * 8 + e;
                unsigned short h, l;
                split1(vv[jj], h, l);
                VTh[off] = h; VTl[off] = l;
            }
        }
        if (t < SUBT) mrw[t] = mask[(size_t)b * S_ + sb + t];
        __syncthreads();

        // ---- scores: main (wave = s-tile) ----
        {
            const int ts = w;
#pragma unroll
            for (int at = 0; at < 3; at++) {
                f32x4 a4 = (f32x4){0.f, 0.f, 0.f, 0.f};
#pragma unroll
                for (int ks = 0; ks < 2; ks++) {
                    size_t oA = ((((size_t)bh * 3 + at) * 2 + ks) * 64 + lane) * 8;
                    short8v gh = *(const short8v*)&AG1h[oA];
                    short8v gl = *(const short8v*)&AG1l[oA];
                    short8v kh2 = *(const short8v*)&KFh[((ts * 2 + ks) * 64 + lane) * 8];
                    short8v kl2 = *(const short8v*)&KFl[((ts * 2 + ks) * 64 + lane) * 8];
                    a4 = __builtin_amdgcn_mfma_f32_16x16x32_bf16(gh, kh2, a4, 0, 0, 0);
                    a4 = __builtin_amdgcn_mfma_f32_16x16x32_bf16(gl, kh2, a4, 0, 0, 0);
                    a4 = __builtin_amdgcn_mfma_f32_16x16x32_bf16(gh, kl2, a4, 0, 0, 0);
                }
                *(f32x4*)&sc[ts * 16 + fr][at * 16 + kg * 4] = a4;
            }
        }
        // ---- scores: bias band (7 j-tiles over 4 waves) ----
        for (int ut = w; ut < 7; ut += 4) {
            const int u = u0 + ut;
#pragma unroll
            for (int at = 0; at < 3; at++) {
                f32x4 a4 = (f32x4){0.f, 0.f, 0.f, 0.f};
#pragma unroll
                for (int ks = 0; ks < 2; ks++) {
                    size_t oA = ((((size_t)bh * 3 + at) * 2 + ks) * 64 + lane) * 8;
                    short8v gh = *(const short8v*)&AG1h[oA];
                    short8v gl = *(const short8v*)&AG1l[oA];
                    size_t oD = (((size_t)u * 2 + ks) * 64 + lane) * 8;
                    short8v dh = *(const short8v*)&D0h[oD];
                    short8v dl = *(const short8v*)&D0l[oD];
                    a4 = __builtin_amdgcn_mfma_f32_16x16x32_bf16(gh, dh, a4, 0, 0, 0);
                    a4 = __builtin_amdgcn_mfma_f32_16x16x32_bf16(gl, dh, a4, 0, 0, 0);
                    a4 = __builtin_amdgcn_mfma_f32_16x16x32_bf16(gh, dl, a4, 0, 0, 0);
                }
                *(f32x4*)&scp[ut * 16 + fr][at * 16 + kg * 4] = a4;
            }
        }
        __syncthreads();

        // ---- combine: sc += band bias (jrel = a+63-sl) + mask ----
        for (int i = t; i < SUBT * A_; i += 256) {
            int rr = i / 40, aa = i - rr * 40;
            sc[rr][aa] += scp[aa + 63 - rr][aa] + mrw[rr];
        }
        __syncthreads();
        // ---- proven online-softmax split reductions ----
        if (t < 240) {
            int a = t % 40, r6 = t / 40;
            float mx = -INFINITY;
            for (int i = r6; i < SUBT; i += 6) mx = fmaxf(mx, sc[i][a]);
            pm6[r6][a] = mx;
        }
        __syncthreads();
        if (t < A_) {
            float lm = pm6[0][t];
#pragma unroll
            for (int r6 = 1; r6 < 6; r6++) lm = fmaxf(lm, pm6[r6][t]);
            float mnew = fmaxf(mrow[t], lm);
            resc[t] = __expf(mrow[t] - mnew);
            mrow[t] = mnew;
        }
        __syncthreads();
        for (int i = t; i < SUBT * A_; i += 256) {
            int rr = i / 40, aa = i - rr * 40;
            sc[rr][aa] = __expf(sc[rr][aa] - mrow[aa]);
        }
        __syncthreads();
        if (t < 240) {
            int a = t % 40, r6 = t / 40;
            float sm = 0.0f;
            for (int i = r6; i < SUBT; i += 6) sm += sc[i][a];
            pm6[r6][a] = sm;
        }
        __syncthreads();
        if (t < A_) {
            float ls = pm6[0][t] + pm6[1][t] + pm6[2][t] + pm6[3][t] + pm6[4][t] + pm6[5][t];
            lrow[t] = lrow[t] * resc[t] + ls;
        }
        __syncthreads();

        // ---- P -> bf16 fragment-major (overlaid on KF; KF dead) ----
        for (int g = t; g < 384; g += 256) {
            int pl = g & 63;           // lane slot
            int c = g >> 6;            // at*2 + ks2
            int at = c >> 1, ks2 = c & 1;
            int a = at * 16 + (pl & 15);
            int sl0 = ks2 * 32 + (pl >> 4) * 8;
            float xv[8];
#pragma unroll
            for (int e = 0; e < 8; e++)
                xv[e] = (a < A_) ? sc[sl0 + e][a] : 0.f;
            int4 hi, lo;
            split8c(xv, hi, lo);
            *(int4*)&KFh[g * 8] = hi;   // PF overlay
            *(int4*)&KFl[g * 8] = lo;
        }
        __syncthreads();

        // ---- PV: wave = d-tile; acc[at] = acc*resc + P x V^T ----
        {
            const int dt = w;
#pragma unroll
            for (int at = 0; at < 3; at++) {
                f32x4 a4 = acc3[at];
#pragma unroll
                for (int p = 0; p < 4; p++) {
                    int a = at * 16 + kg * 4 + p;
                    float rs = (a < A_) ? resc[a] : 0.f;
                    a4[p] *= rs;
                }
#pragma unroll
                for (int ks2 = 0; ks2 < 2; ks2++) {
                    short8v ph = *(const short8v*)&KFh[((at * 2 + ks2) * 64 + lane) * 8];
                    short8v pll = *(const short8v*)&KFl[((at * 2 + ks2) * 64 + lane) * 8];
                    short8v vh = *(const short8v*)&VTh[((dt * 2 + ks2) * 64 + lane) * 8];
                    short8v vl = *(const short8v*)&VTl[((dt * 2 + ks2) * 64 + lane) * 8];
                    a4 = __builtin_amdgcn_mfma_f32_16x16x32_bf16(ph, vh, a4, 0, 0, 0);
                    a4 = __builtin_amdgcn_mfma_f32_16x16x32_bf16(pll, vh, a4, 0, 0, 0);
                    a4 = __builtin_amdgcn_mfma_f32_16x16x32_bf16(ph, vl, a4, 0, 0, 0);
                }
                acc3[at] = a4;
            }
        }
    }
    __syncthreads();

    // ---- write partials ----
    {
        const int dt = w;
#pragma unroll
        for (int at = 0; at < 3; at++) {
#pragma unroll
            for (int p = 0; p < 4; p++) {
                int a = at * 16 + kg * 4 + p;
                if (a < A_)
                    Pacc[(((size_t)(bh * CH1 + q) * A_) + a) * D_ + dt * 16 + fr] = acc3[at][p];
            }
        }
    }
    if (t < A_) {
        Pm[(size_t)(bh * CH1 + q) * A_ + t] = mrow[t];
        Pl[(size_t)(bh * CH1 + q) * A_ + t] = lrow[t];
    }
}

// ---------------- stage 1 reduce ----------------
__global__ __launch_bounds__(256) void stage1_reduce(
    const float* __restrict__ Pacc, const float* __restrict__ Pm,
    const float* __restrict__ Pl, float* __restrict__ AgV)
{
    const int bh = blockIdx.x;
    const int t = threadIdx.x;
    __shared__ float F[CH1][A_], Linv[A_];
    if (t < A_) {
        float M = -INFINITY;
#pragma unroll
        for (int q = 0; q < CH1; q++) M = fmaxf(M, Pm[(size_t)(bh * CH1 + q) * A_ + t]);
        float L = 0.0f;
#pragma unroll
        for (int q = 0; q < CH1; q++) {
            float f = __expf(Pm[(size_t)(bh * CH1 + q) * A_ + t] - M);
            F[q][t] = f;
            L = fmaf(f, Pl[(size_t)(bh * CH1 + q) * A_ + t], L);
        }
        Linv[t] = 1.0f / L;
    }
    __syncthreads();
#pragma unroll
    for (int ii = 0; ii < 3; ii++) {
        int i = t + ii * 256;
        if (i < A_ * 16) {
            int a = i >> 4, d4 = i & 15;
            float4 s4 = make_float4(0.f, 0.f, 0.f, 0.f);
            for (int q = 0; q < CH1; q++) {
                float f = F[q][a];
                float4 p4 = *(const float4*)&Pacc[(((size_t)(bh * CH1 + q) * A_) + a) * D_ + d4 * 4];
                s4.x = fmaf(f, p4.x, s4.x);
                s4.y = fmaf(f, p4.y, s4.y);
                s4.z = fmaf(f, p4.z, s4.z);
                s4.w = fmaf(f, p4.w, s4.w);
            }
            float inv = Linv[a];
            s4.x *= inv; s4.y *= inv; s4.z *= inv; s4.w *= inv;
            *(float4*)&AgV[(size_t)bh * (A_ * D_) + a * D_ + d4 * 4] = s4;
        }
    }
}

// ------- stage 2 MFMA v3: fragment-major operands, Q via LDS reshuffle, 64 s/block ------
__global__ __launch_bounds__(256, 2) void stage2_mfma(
    const float* __restrict__ Qg,
    const unsigned short* __restrict__ AGFh, const unsigned short* __restrict__ AGFl,
    const unsigned short* __restrict__ DFh,  const unsigned short* __restrict__ DFl,
    const unsigned short* __restrict__ AVFh, const unsigned short* __restrict__ AVFl,
    float* __restrict__ Out)
{
    const int sbk = blockIdx.x;      // 0..31
    const int bh  = blockIdx.y;      // 0..191
    const int b = bh / H_, h = bh % H_;
    const int s0 = sbk * 64;
    const int base_u = 4 * sbk + 125;

    __shared__ unsigned short Qfh[8 * 64 * 8], Qfl[8 * 64 * 8];
    __shared__ float scm[64][52];
    __shared__ float scp[64][68];
    __shared__ unsigned short PAh[64][72], PAl[64][72];

    const int t = threadIdx.x;
    const int lane = t & 63, ts = t >> 6;
    const int fr = lane & 15, kg = lane >> 4;

    {
        const int r = t >> 2, c0 = (t & 3) * 16;
        const float* qp = Qg + ((size_t)bh * S_ + s0 + r) * D_ + c0;
        float xa[8], xb[8];
        float4 f0 = *(const float4*)(qp);
        float4 f1 = *(const float4*)(qp + 4);
        float4 f2 = *(const float4*)(qp + 8);
        float4 f3 = *(const float4*)(qp + 12);
        xa[0]=f0.x; xa[1]=f0.y; xa[2]=f0.z; xa[3]=f0.w;
        xa[4]=f1.x; xa[5]=f1.y; xa[6]=f1.z; xa[7]=f1.w;
        xb[0]=f2.x; xb[1]=f2.y; xb[2]=f2.z; xb[3]=f2.w;
        xb[4]=f3.x; xb[5]=f3.y; xb[6]=f3.z; xb[7]=f3.w;
        int4 h0, l0, h1, l1;
        split8c(xa, h0, l0);
        split8c(xb, h1, l1);
        const int tsr = r >> 4, frr = r & 15;
        const int c8a = (t & 3) * 2, c8b = c8a + 1;
        const int oa = ((tsr * 2 + (c8a >> 2)) * 64 + (((c8a & 3) << 4) | frr)) * 8;
        const int ob = ((tsr * 2 + (c8b >> 2)) * 64 + (((c8b & 3) << 4) | frr)) * 8;
        *(int4*)&Qfh[oa] = h0;  *(int4*)&Qfl[oa] = l0;
        *(int4*)&Qfh[ob] = h1;  *(int4*)&Qfl[ob] = l1;
    }
    __syncthreads();

    short8v qh[2], ql[2];
#pragma unroll
    for (int ks = 0; ks < 2; ks++) {
        qh[ks] = *(const short8v*)&Qfh[((ts * 2 + ks) * 64 + lane) * 8];
        ql[ks] = *(const short8v*)&Qfl[((ts * 2 + ks) * 64 + lane) * 8];
    }

#pragma unroll
    for (int at = 0; at < 3; at++) {
        f32x4 acc = (f32x4){0.f, 0.f, 0.f, 0.f};
#pragma unroll
        for (int ks = 0; ks < 2; ks++) {
            size_t o = ((((size_t)bh * 3 + at) * 2 + ks) * 64 + lane) * 8;
            short8v chv = *(const short8v*)&AGFh[o];
            short8v clv = *(const short8v*)&AGFl[o];
            acc = __builtin_amdgcn_mfma_f32_16x16x32_bf16(chv, qh[ks], acc, 0, 0, 0);
            acc = __builtin_amdgcn_mfma_f32_16x16x32_bf16(clv, qh[ks], acc, 0, 0, 0);
            acc = __builtin_amdgcn_mfma_f32_16x16x32_bf16(chv, ql[ks], acc, 0, 0, 0);
        }
        *(f32x4*)&scm[ts * 16 + fr][at * 16 + kg * 4] = acc;
    }
#pragma unroll
    for (int o4 = 0; o4 < 4; o4++) {
        f32x4 acc = (f32x4){0.f, 0.f, 0.f, 0.f};
        const int u = base_u + ts + o4;
#pragma unroll
        for (int ks = 0; ks < 2; ks++) {
            size_t o = (((size_t)u * 2 + ks) * 64 + lane) * 8;
            short8v chv = *(const short8v*)&DFh[o];
            short8v clv = *(const short8v*)&DFl[o];
            acc = __builtin_amdgcn_mfma_f32_16x16x32_bf16(chv, qh[ks], acc, 0, 0, 0);
            acc = __builtin_amdgcn_mfma_f32_16x16x32_bf16(clv, qh[ks], acc, 0, 0, 0);
            acc = __builtin_amdgcn_mfma_f32_16x16x32_bf16(chv, ql[ks], acc, 0, 0, 0);
        }
        *(f32x4*)&scp[ts * 16 + fr][o4 * 16 + kg * 4] = acc;
    }
    __syncthreads();

    {
        const int r = t >> 2, dq = t & 3;
        const int base = (r & 15) + 39;
        float val[10];
#pragma unroll
        for (int i = 0; i < 10; i++) {
            int a = dq * 10 + i;
            val[i] = scm[r][a] + scp[r][base - a];
        }
        float mx = -INFINITY;
#pragma unroll
        for (int i = 0; i < 10; i++) mx = fmaxf(mx, val[i]);
        mx = fmaxf(mx, __shfl_xor(mx, 1));
        mx = fmaxf(mx, __shfl_xor(mx, 2));
        float sum = 0.f;
#pragma unroll
        for (int i = 0; i < 10; i++) { val[i] = __expf(val[i] - mx); sum += val[i]; }
        sum += __shfl_xor(sum, 1);
        sum += __shfl_xor(sum, 2);
        float inv = 1.0f / sum;
        unsigned* ph = (unsigned*)&PAh[r][0];
        unsigned* pl = (unsigned*)&PAl[r][0];
#pragma unroll
        for (int i = 0; i < 5; i++) {
            unsigned short h0, l0, h1, l1;
            split1(val[2 * i] * inv, h0, l0);
            split1(val[2 * i + 1] * inv, h1, l1);
            ph[dq * 5 + i] = (unsigned)h0 | ((unsigned)h1 << 16);
            pl[dq * 5 + i] = (unsigned)l0 | ((unsigned)l1 << 16);
        }
#pragma unroll
        for (int i = 0; i < 3; i++) { ph[20 + dq * 3 + i] = 0u; pl[20 + dq * 3 + i] = 0u; }
    }
    __syncthreads();

    short8v ph8[2], pl8[2];
#pragma unroll
    for (int ks = 0; ks < 2; ks++) {
        ph8[ks] = *(const short8v*)&PAh[ts * 16 + fr][ks * 32 + kg * 8];
        pl8[ks] = *(const short8v*)&PAl[ts * 16 + fr][ks * 32 + kg * 8];
    }
#pragma unroll
    for (int nt = 0; nt < 4; nt++) {
        f32x4 acc = (f32x4){0.f, 0.f, 0.f, 0.f};
#pragma unroll
        for (int ks = 0; ks < 2; ks++) {
            size_t o = ((((size_t)bh * 4 + nt) * 2 + ks) * 64 + lane) * 8;
            short8v vh = *(const short8v*)&AVFh[o];
            short8v vl = *(const short8v*)&AVFl[o];
            acc = __builtin_amdgcn_mfma_f32_16x16x32_bf16(ph8[ks], vh, acc, 0, 0, 0);
            acc = __builtin_amdgcn_mfma_f32_16x16x32_bf16(pl8[ks], vh, acc, 0, 0, 0);
            acc = __builtin_amdgcn_mfma_f32_16x16x32_bf16(ph8[ks], vl, acc, 0, 0, 0);
        }
        const int d = nt * 16 + fr;
        float* op = Out + ((size_t)b * S_ + s0 + ts * 16 + kg * 4) * HID + h * D_ + d;
#pragma unroll
        for (int r = 0; r < 4; r++)
            op[(size_t)r * HID] = acc[r];
    }
}

extern "C" void kernel_launch(void* const* d_in, const int* in_sizes, int n_in,
                              void* d_out, int out_size, void* d_ws, size_t ws_size,
                              hipStream_t stream) {
    const float* hs   = (const float*)d_in[0];
    const float* mask = (const float*)d_in[1];
    const float* Wq   = (const float*)d_in[2];
    const float* bq   = (const float*)d_in[3];
    const float* Wk   = (const float*)d_in[4];
    const float* bk   = (const float*)d_in[5];
    const float* Wv   = (const float*)d_in[6];
    const float* bv   = (const float*)d_in[7];
    const float* dist = (const float*)d_in[8];
    float* out = (float*)d_out;

    float* ws = (float*)d_ws;
    const size_t QKV = (size_t)B_ * H_ * S_ * D_;
    const size_t AG  = (size_t)B_ * H_ * A_ * D_;
    float* Q     = ws;
    float* K     = ws + QKV;
    float* V     = ws + 2 * QKV;
    float* Agent = ws + 3 * QKV;
    float* AgV   = Agent + AG;
    float* Pacc  = AgV + AG;
    float* Pm    = Pacc + (size_t)B_ * H_ * CH1 * A_ * D_;
    float* Pl    = Pm + (size_t)B_ * H_ * CH1 * A_;
    unsigned short* Wth = (unsigned short*)(Pl + (size_t)B_ * H_ * CH1 * A_);
    unsigned short* Wtl = Wth + (size_t)3 * HID * HID;
    unsigned short* DFh = Wtl + (size_t)3 * HID * HID;      // 262,144
    unsigned short* DFl = DFh + (size_t)262144;
    unsigned short* AGFh = DFl + (size_t)262144;            // 589,824
    unsigned short* AGFl = AGFh + (size_t)589824;
    unsigned short* AVFh = AGFl + (size_t)589824;           // 786,432
    unsigned short* AVFl = AVFh + (size_t)786432;
    unsigned short* AG1h = AVFl + (size_t)786432;           // 589,824 (unscaled)
    unsigned short* AG1l = AG1h + (size_t)589824;
    unsigned short* D0h  = AG1l + (size_t)589824;           // 131*2*64*8 = 134,144
    unsigned short* D0l  = D0h + (size_t)134144;
    // total ws ~340 MB (within known-good <=393 MB budget)

    wt_convert<<<(3 * 192 * 768 + 255) / 256, 256, 0, stream>>>(Wq, Wk, Wv, Wth, Wtl);
    dist_frag<<<(256 * 2 * 64 + 255) / 256, 256, 0, stream>>>(dist, DFh, DFl);
    dist_frag0<<<(131 * 2 * 64 + 255) / 256, 256, 0, stream>>>(dist, D0h, D0l);
    qkv_z<<<2304, 512, 0, stream>>>(hs, Wth, Wtl, bq, bk, bv, Q, K, V);
    agent_pool<<<(B_ * H_ * A_ * D_ + 255) / 256, 256, 0, stream>>>(Q, Agent);
    ag_frag<<<(192 * 3 * 2 * 64 + 255) / 256, 256, 0, stream>>>(Agent, AGFh, AGFl, SCALE_);
    ag_frag<<<(192 * 3 * 2 * 64 + 255) / 256, 256, 0, stream>>>(Agent, AG1h, AG1l, 1.0f);
    dim3 g1(CH1, B_ * H_);
    stage1_mfma<<<g1, 256, 0, stream>>>(K, V, AG1h, AG1l, D0h, D0l, mask, Pacc, Pm, Pl);
    stage1_reduce<<<B_ * H_, 256, 0, stream>>>(Pacc, Pm, Pl, AgV);
    avt_frag<<<(192 * 4 * 2 * 64 + 255) / 256, 256, 0, stream>>>(AgV, AVFh, AVFl);
    dim3 g2(32, B_ * H_);
    stage2_mfma<<<g2, 256, 0, stream>>>(Q, AGFh, AGFl, DFh, DFl, AVFh, AVFl, out);
}

// Round 14
// 563.415 us; speedup vs baseline: 1.3125x; 1.0269x over previous
//
#include <hip/hip_runtime.h>
#include <math.h>

#define B_ 16
#define S_ 2048
#define H_ 12
#define D_ 64
#define HID 768
#define A_ 40
#define SCALE_ 0.125f
#define CH1 8          // stage1 s-chunks per (b,h)
#define SUBT 64        // s per subtile
#define NSUB 4         // subtiles per block (256 s per block)

typedef __attribute__((ext_vector_type(8))) short short8v;    // 8 bf16 (4 VGPR)
typedef __attribute__((ext_vector_type(4))) float f32x4;
typedef __attribute__((ext_vector_type(16))) float f32x16;    // 32x32 MFMA C/D

__device__ __forceinline__ unsigned f2bf_bits(float x) {
    unsigned u = __float_as_uint(x);
    return (u + 0x7FFFu + ((u >> 16) & 1u)) >> 16;   // RTNE
}

__device__ __forceinline__ void split1(float v, unsigned short& h, unsigned short& l) {
    __bf16 bh = (__bf16)v;
    float hf = (float)bh;
    __bf16 bl = (__bf16)(v - hf);
    h = __builtin_bit_cast(unsigned short, bh);
    l = __builtin_bit_cast(unsigned short, bl);
}

// split 8 fp32 -> hi/lo bf16 via native __bf16 casts (RTNE)
__device__ __forceinline__ void split8c(const float* x, int4& hi, int4& lo) {
    unsigned h[8], l[8];
#pragma unroll
    for (int i = 0; i < 8; i++) {
        __bf16 bh = (__bf16)x[i];
        float hf = (float)bh;
        __bf16 bl = (__bf16)(x[i] - hf);
        h[i] = (unsigned)__builtin_bit_cast(unsigned short, bh);
        l[i] = (unsigned)__builtin_bit_cast(unsigned short, bl);
    }
    hi = make_int4((int)(h[0] | (h[1] << 16)), (int)(h[2] | (h[3] << 16)),
                   (int)(h[4] | (h[5] << 16)), (int)(h[6] | (h[7] << 16)));
    lo = make_int4((int)(l[0] | (l[1] << 16)), (int)(l[2] | (l[3] << 16)),
                   (int)(l[4] | (l[5] << 16)), (int)(l[6] | (l[7] << 16)));
}

// ---------------- W transpose + bf16 hi/lo split: Wt[z][n][k] ----------------
__global__ void wt_convert(const float* __restrict__ Wq, const float* __restrict__ Wk,
                           const float* __restrict__ Wv,
                           unsigned short* __restrict__ Wth, unsigned short* __restrict__ Wtl)
{
    int idx = blockIdx.x * 256 + threadIdx.x;          // 3 * 192 * 768
    if (idx >= 3 * 192 * 768) return;
    int n  = idx % 768;
    int kc = (idx / 768) % 192;
    int z  = idx / (768 * 192);
    const float* W = (z == 0) ? Wq : (z == 1) ? Wk : Wv;
    unsigned short h4[4], l4[4];
#pragma unroll
    for (int i = 0; i < 4; i++) {
        float x = W[(size_t)(4 * kc + i) * HID + n];
        unsigned hb = f2bf_bits(x);
        float hf = __uint_as_float(hb << 16);
        h4[i] = (unsigned short)hb;
        l4[i] = (unsigned short)f2bf_bits(x - hf);
    }
    size_t o = ((size_t)z * HID + n) * HID + 4 * kc;
    *(ushort4*)&Wth[o] = make_ushort4(h4[0], h4[1], h4[2], h4[3]);
    *(ushort4*)&Wtl[o] = make_ushort4(l4[0], l4[1], l4[2], l4[3]);
}

// ------- dist -> frag-major tiles rows 8+16u (stage2 lattice), u<256 --------
__global__ void dist_frag(const float* __restrict__ dist,
                          unsigned short* __restrict__ DFh, unsigned short* __restrict__ DFl)
{
    int g = blockIdx.x * 256 + threadIdx.x;   // 256 * 2 * 64
    if (g >= 256 * 2 * 64) return;
    int lane = g & 63;
    int ks = (g >> 6) & 1;
    int u  = g >> 7;
    int row = 8 + u * 16 + (lane & 15);
    int col = ks * 32 + ((lane >> 4) << 3);
    float xv[8];
#pragma unroll
    for (int j = 0; j < 8; j++)
        xv[j] = (row < 4095) ? dist[(size_t)row * D_ + col + j] : 0.f;
    int4 hi, lo;
    split8c(xv, hi, lo);
    *(int4*)&DFh[(size_t)g * 8] = hi;
    *(int4*)&DFl[(size_t)g * 8] = lo;
}

// ------- dist -> frag-major tiles rows 16u (stage1 lattice), u<131 ----------
__global__ void dist_frag0(const float* __restrict__ dist,
                           unsigned short* __restrict__ Dh, unsigned short* __restrict__ Dl)
{
    int g = blockIdx.x * 256 + threadIdx.x;   // 131 * 2 * 64
    if (g >= 131 * 2 * 64) return;
    int lane = g & 63;
    int ks = (g >> 6) & 1;
    int u  = g >> 7;
    int row = u * 16 + (lane & 15);           // <= 2095, all real
    int col = ks * 32 + ((lane >> 4) << 3);
    float xv[8];
#pragma unroll
    for (int j = 0; j < 8; j++) xv[j] = dist[(size_t)row * D_ + col + j];
    int4 hi, lo;
    split8c(xv, hi, lo);
    *(int4*)&Dh[(size_t)g * 8] = hi;
    *(int4*)&Dl[(size_t)g * 8] = lo;
}

// ------- scale*agent -> fragment-major: [bh][at<3][ks][lane][8] (a>=40 zero) ---------
__global__ void ag_frag(const float* __restrict__ Ag,
                        unsigned short* __restrict__ Gh, unsigned short* __restrict__ Gl,
                        float scale)
{
    int g = blockIdx.x * 256 + threadIdx.x;   // 192*3*2*64
    if (g >= 192 * 3 * 2 * 64) return;
    int lane = g & 63;
    int r = g >> 6;
    int ks = r & 1; r >>= 1;
    int at = r % 3;
    int bh = r / 3;
    int a = at * 16 + (lane & 15);
    int col = ks * 32 + ((lane >> 4) << 3);
    float xv[8];
#pragma unroll
    for (int j = 0; j < 8; j++)
        xv[j] = (a < A_) ? scale * Ag[((size_t)bh * A_ + a) * D_ + col + j] : 0.f;
    int4 hi, lo;
    split8c(xv, hi, lo);
    *(int4*)&Gh[(size_t)g * 8] = hi;
    *(int4*)&Gl[(size_t)g * 8] = lo;
}

// ------- AgV^T -> fragment-major: [bh][nt<4][ks][lane][8] rows=d, cols=a ----------
__global__ void avt_frag(const float* __restrict__ AgV,
                         unsigned short* __restrict__ Vh, unsigned short* __restrict__ Vl)
{
    int g = blockIdx.x * 256 + threadIdx.x;   // 192*4*2*64
    if (g >= 192 * 4 * 2 * 64) return;
    int lane = g & 63;
    int r = g >> 6;
    int ks = r & 1; r >>= 1;
    int nt = r & 3;
    int bh = r >> 2;
    int d = nt * 16 + (lane & 15);
    int a0 = ks * 32 + ((lane >> 4) << 3);
    float xv[8];
#pragma unroll
    for (int j = 0; j < 8; j++) {
        int a = a0 + j;
        xv[j] = (a < A_) ? AgV[((size_t)bh * A_ + a) * D_ + d] : 0.f;
    }
    int4 hi, lo;
    split8c(xv, hi, lo);
    *(int4*)&Vh[(size_t)g * 8] = hi;
    *(int4*)&Vl[(size_t)g * 8] = lo;
}

// ---------------- QKV: bf16x3 MFMA GEMM (32x32x16), 128x256 tile, XCD-swizzled ----------
__global__ __launch_bounds__(512, 2) void qkv_z(
    const float* __restrict__ X,
    const unsigned short* __restrict__ Wth, const unsigned short* __restrict__ Wtl,
    const float* __restrict__ bq, const float* __restrict__ bk, const float* __restrict__ bv,
    float* __restrict__ Q, float* __restrict__ K, float* __restrict__ V)
{
    const int L   = blockIdx.x;
    const int k8  = L & 7, sl_ = L >> 3;
    const int mt  = k8 * 32 + sl_ / 9;
    const int sub = sl_ % 9;
    const int nt  = sub % 3, zz = sub / 3;
    const int m0 = mt * 128, n0 = nt * 256;

    const float* __restrict__ bias = (zz == 0) ? bq : (zz == 1) ? bk : bv;
    float* __restrict__ Out        = (zz == 0) ? Q  : (zz == 1) ? K  : V;
    const unsigned short* __restrict__ Bhg = Wth + (size_t)zz * HID * HID;
    const unsigned short* __restrict__ Blg = Wtl + (size_t)zz * HID * HID;

    __shared__ unsigned short Ah[128][40];
    __shared__ unsigned short Al[128][40];
    __shared__ unsigned short Bh[256][40];
    __shared__ unsigned short Bl[256][40];

    const int t = threadIdx.x;
    const int lane = t & 63, w = t >> 6;
    const int wm = (w & 1) * 64, wn = (w >> 1) * 64;
    const int r32 = lane & 31, kh = lane >> 5;

    const int sr = t >> 2, sca = (t & 3) * 8;
    const int sb = t >> 1, scb = (t & 1) * 16;

    f32x16 acc[2][2];
#pragma unroll
    for (int i = 0; i < 2; i++)
#pragma unroll
        for (int j = 0; j < 2; j++)
#pragma unroll
            for (int p = 0; p < 16; p++) acc[i][j][p] = 0.f;

    for (int k0 = 0; k0 < HID; k0 += 32) {
        float xv[8];
        const float* xp = X + (size_t)(m0 + sr) * HID + k0 + sca;
        float4 f0 = *(const float4*)xp;
        float4 f1 = *(const float4*)(xp + 4);
        xv[0] = f0.x; xv[1] = f0.y; xv[2] = f0.z; xv[3] = f0.w;
        xv[4] = f1.x; xv[5] = f1.y; xv[6] = f1.z; xv[7] = f1.w;
        int4 ah, al;
        split8c(xv, ah, al);
        size_t bo = (size_t)(n0 + sb) * HID + k0 + scb;
        int4 bh0 = *(const int4*)&Bhg[bo];
        int4 bh1 = *(const int4*)&Bhg[bo + 8];
        int4 bl0 = *(const int4*)&Blg[bo];
        int4 bl1 = *(const int4*)&Blg[bo + 8];

        __syncthreads();
        *(int4*)&Ah[sr][sca] = ah;
        *(int4*)&Al[sr][sca] = al;
        *(int4*)&Bh[sb][scb]     = bh0;  *(int4*)&Bh[sb][scb + 8] = bh1;
        *(int4*)&Bl[sb][scb]     = bl0;  *(int4*)&Bl[sb][scb + 8] = bl1;
        __syncthreads();

#pragma unroll
        for (int ks = 0; ks < 2; ks++) {
            const int ko = ks * 16 + kh * 8;
            short8v a_h[2], a_l[2], b_h[2], b_l[2];
#pragma unroll
            for (int i = 0; i < 2; i++) {
                a_h[i] = *(const short8v*)&Ah[wm + i * 32 + r32][ko];
                a_l[i] = *(const short8v*)&Al[wm + i * 32 + r32][ko];
                b_h[i] = *(const short8v*)&Bh[wn + i * 32 + r32][ko];
                b_l[i] = *(const short8v*)&Bl[wn + i * 32 + r32][ko];
            }
#pragma unroll
            for (int i = 0; i < 2; i++)
#pragma unroll
                for (int j = 0; j < 2; j++) {
                    acc[i][j] = __builtin_amdgcn_mfma_f32_32x32x16_bf16(a_h[i], b_h[j], acc[i][j], 0, 0, 0);
                    acc[i][j] = __builtin_amdgcn_mfma_f32_32x32x16_bf16(a_l[i], b_h[j], acc[i][j], 0, 0, 0);
                    acc[i][j] = __builtin_amdgcn_mfma_f32_32x32x16_bf16(a_h[i], b_l[j], acc[i][j], 0, 0, 0);
                }
        }
    }

    const float scl = (zz == 1) ? SCALE_ : 1.0f;
#pragma unroll
    for (int j = 0; j < 2; j++) {
        int n = n0 + wn + j * 32 + r32;
        float bj = bias[n];
        int h = n >> 6, d = n & 63;
#pragma unroll
        for (int i = 0; i < 2; i++) {
#pragma unroll
            for (int p = 0; p < 16; p++) {
                int m = m0 + wm + i * 32 + (p & 3) + 8 * (p >> 2) + 4 * kh;
                int b = m >> 11, s = m & 2047;
                Out[(((size_t)b * H_ + h) * S_ + s) * D_ + d] = (acc[i][j][p] + bj) * scl;
            }
        }
    }
}

// ---------------- agent pooling ----------------
__global__ void agent_pool(const float* __restrict__ Q, float* __restrict__ Ag)
{
    int idx = blockIdx.x * 256 + threadIdx.x;
    if (idx >= B_ * H_ * A_ * D_) return;
    int d  = idx & 63;
    int a  = (idx >> 6) % A_;
    int bh = idx / (A_ * D_);
    float src = ((float)a + 0.5f) * (2048.0f / 40.0f) - 0.5f;
    src = fminf(fmaxf(src, 0.0f), 2047.0f);
    int lo = (int)floorf(src);
    int hi = min(lo + 1, S_ - 1);
    float w = src - (float)lo;
    const float* base = Q + (size_t)bh * (S_ * D_);
    Ag[idx] = base[lo * D_ + d] * (1.0f - w) + base[hi * D_ + d] * w;
}

// ---------------- stage 1 MFMA (round-13 proven) ----------------
__global__ __launch_bounds__(256, 2) void stage1_mfma(
    const float* __restrict__ Kl, const float* __restrict__ Vl,
    const unsigned short* __restrict__ AG1h, const unsigned short* __restrict__ AG1l,
    const unsigned short* __restrict__ D0h,  const unsigned short* __restrict__ D0l,
    const float* __restrict__ mask,
    float* __restrict__ Pacc, float* __restrict__ Pm, float* __restrict__ Pl)
{
    const int q  = blockIdx.x;       // 0..7
    const int bh = blockIdx.y;       // 0..191
    const int b  = bh / H_;
    const int s0 = q * (NSUB * SUBT);
    const float* __restrict__ kb = Kl + (size_t)bh * (S_ * D_);
    const float* __restrict__ vb = Vl + (size_t)bh * (S_ * D_);

    __shared__ unsigned short KFh[4096], KFl[4096];
    __shared__ unsigned short VTh[4096], VTl[4096];
    __shared__ float sc[SUBT][52];
    __shared__ float scp[112][52];
    __shared__ float pm6[6][A_];
    __shared__ float mrow[A_], lrow[A_], resc[A_], mrw[SUBT];

    const int t = threadIdx.x;
    const int lane = t & 63, w = t >> 6;
    const int fr = lane & 15, kg = lane >> 4;

    if (t < A_) { mrow[t] = -INFINITY; lrow[t] = 0.0f; }

    f32x4 acc3[3];
#pragma unroll
    for (int at = 0; at < 3; at++) acc3[at] = (f32x4){0.f, 0.f, 0.f, 0.f};

    for (int st = 0; st < NSUB; st++) {
        const int sb = s0 + st * SUBT;
        const int u0 = (1984 - sb) >> 4;

        __syncthreads();

        {
            const int r = t >> 2, c0 = (t & 3) * 16;
            const float* kp = kb + (size_t)(sb + r) * D_ + c0;
            float xa[8], xb[8];
            float4 f0 = *(const float4*)(kp);
            float4 f1 = *(const float4*)(kp + 4);
            float4 f2 = *(const float4*)(kp + 8);
            float4 f3 = *(const float4*)(kp + 12);
            xa[0]=f0.x; xa[1]=f0.y; xa[2]=f0.z; xa[3]=f0.w;
            xa[4]=f1.x; xa[5]=f1.y; xa[6]=f1.z; xa[7]=f1.w;
            xb[0]=f2.x; xb[1]=f2.y; xb[2]=f2.z; xb[3]=f2.w;
            xb[4]=f3.x; xb[5]=f3.y; xb[6]=f3.z; xb[7]=f3.w;
            int4 h0, l0, h1, l1;
            split8c(xa, h0, l0);
            split8c(xb, h1, l1);
            const int tsr = r >> 4, frr = r & 15;
            const int c8a = (t & 3) * 2, c8b = c8a + 1;
            const int oa = ((tsr * 2 + (c8a >> 2)) * 64 + (((c8a & 3) << 4) | frr)) * 8;
            const int ob = ((tsr * 2 + (c8b >> 2)) * 64 + (((c8b & 3) << 4) | frr)) * 8;
            *(int4*)&KFh[oa] = h0;  *(int4*)&KFl[oa] = l0;
            *(int4*)&KFh[ob] = h1;  *(int4*)&KFl[ob] = l1;
        }
        {
            const int r = t >> 2, c0 = (t & 3) * 16;
            const float* vp = vb + (size_t)(sb + r) * D_ + c0;
            float vv[16];
            float4 g0 = *(const float4*)(vp);
            float4 g1 = *(const float4*)(vp + 4);
            float4 g2 = *(const float4*)(vp + 8);
            float4 g3 = *(const float4*)(vp + 12);
            vv[0]=g0.x; vv[1]=g0.y; vv[2]=g0.z; vv[3]=g0.w;
            vv[4]=g1.x; vv[5]=g1.y; vv[6]=g1.z; vv[7]=g1.w;
            vv[8]=g2.x; vv[9]=g2.y; vv[10]=g2.z; vv[11]=g2.w;
            vv[12]=g3.x; vv[13]=g3.y; vv[14]=g3.z; vv[15]=g3.w;
            const int ks2 = r >> 5, kgp = (r & 31) >> 3, e = r & 7;
#pragma unroll
            for (int jj = 0; jj < 16; jj++) {
                int d = c0 + jj;
                int off = (((d >> 4) * 2 + ks2) * 64 + kgp * 16 + (d & 15)) * 8 + e;
                unsigned short h, l;
                split1(vv[jj], h, l);
                VTh[off] = h; VTl[off] = l;
            }
        }
        if (t < SUBT) mrw[t] = mask[(size_t)b * S_ + sb + t];
        __syncthreads();

        {
            const int ts = w;
#pragma unroll
            for (int at = 0; at < 3; at++) {
                f32x4 a4 = (f32x4){0.f, 0.f, 0.f, 0.f};
#pragma unroll
                for (int ks = 0; ks < 2; ks++) {
                    size_t oA = ((((size_t)bh * 3 + at) * 2 + ks) * 64 + lane) * 8;
                    short8v gh = *(const short8v*)&AG1h[oA];
                    short8v gl = *(const short8v*)&AG1l[oA];
                    short8v kh2 = *(const short8v*)&KFh[((ts * 2 + ks) * 64 + lane) * 8];
                    short8v kl2 = *(const short8v*)&KFl[((ts * 2 + ks) * 64 + lane) * 8];
                    a4 = __builtin_amdgcn_mfma_f32_16x16x32_bf16(gh, kh2, a4, 0, 0, 0);
                    a4 = __builtin_amdgcn_mfma_f32_16x16x32_bf16(gl, kh2, a4, 0, 0, 0);
                    a4 = __builtin_amdgcn_mfma_f32_16x16x32_bf16(gh, kl2, a4, 0, 0, 0);
                }
                *(f32x4*)&sc[ts * 16 + fr][at * 16 + kg * 4] = a4;
            }
        }
        for (int ut = w; ut < 7; ut += 4) {
            const int u = u0 + ut;
#pragma unroll
            for (int at = 0; at < 3; at++) {
                f32x4 a4 = (f32x4){0.f, 0.f, 0.f, 0.f};
#pragma unroll
                for (int ks = 0; ks < 2; ks++) {
                    size_t oA = ((((size_t)bh * 3 + at) * 2 + ks) * 64 + lane) * 8;
                    short8v gh = *(const short8v*)&AG1h[oA];
                    short8v gl = *(const short8v*)&AG1l[oA];
                    size_t oD = (((size_t)u * 2 + ks) * 64 + lane) * 8;
                    short8v dh = *(const short8v*)&D0h[oD];
                    short8v dl = *(const short8v*)&D0l[oD];
                    a4 = __builtin_amdgcn_mfma_f32_16x16x32_bf16(gh, dh, a4, 0, 0, 0);
                    a4 = __builtin_amdgcn_mfma_f32_16x16x32_bf16(gl, dh, a4, 0, 0, 0);
                    a4 = __builtin_amdgcn_mfma_f32_16x16x32_bf16(gh, dl, a4, 0, 0, 0);
                }
                *(f32x4*)&scp[ut * 16 + fr][at * 16 + kg * 4] = a4;
            }
        }
        __syncthreads();

        for (int i = t; i < SUBT * A_; i += 256) {
            int rr = i / 40, aa = i - rr * 40;
            sc[rr][aa] += scp[aa + 63 - rr][aa] + mrw[rr];
        }
        __syncthreads();
        if (t < 240) {
            int a = t % 40, r6 = t / 40;
            float mx = -INFINITY;
            for (int i = r6; i < SUBT; i += 6) mx = fmaxf(mx, sc[i][a]);
            pm6[r6][a] = mx;
        }
        __syncthreads();
        if (t < A_) {
            float lm = pm6[0][t];
#pragma unroll
            for (int r6 = 1; r6 < 6; r6++) lm = fmaxf(lm, pm6[r6][t]);
            float mnew = fmaxf(mrow[t], lm);
            resc[t] = __expf(mrow[t] - mnew);
            mrow[t] = mnew;
        }
        __syncthreads();
        for (int i = t; i < SUBT * A_; i += 256) {
            int rr = i / 40, aa = i - rr * 40;
            sc[rr][aa] = __expf(sc[rr][aa] - mrow[aa]);
        }
        __syncthreads();
        if (t < 240) {
            int a = t % 40, r6 = t / 40;
            float sm = 0.0f;
            for (int i = r6; i < SUBT; i += 6) sm += sc[i][a];
            pm6[r6][a] = sm;
        }
        __syncthreads();
        if (t < A_) {
            float ls = pm6[0][t] + pm6[1][t] + pm6[2][t] + pm6[3][t] + pm6[4][t] + pm6[5][t];
            lrow[t] = lrow[t] * resc[t] + ls;
        }
        __syncthreads();

        for (int g = t; g < 384; g += 256) {
            int pl = g & 63;
            int c = g >> 6;
            int at = c >> 1, ks2 = c & 1;
            int a = at * 16 + (pl & 15);
            int sl0 = ks2 * 32 + (pl >> 4) * 8;
            float xv[8];
#pragma unroll
            for (int e = 0; e < 8; e++)
                xv[e] = (a < A_) ? sc[sl0 + e][a] : 0.f;
            int4 hi, lo;
            split8c(xv, hi, lo);
            *(int4*)&KFh[g * 8] = hi;
            *(int4*)&KFl[g * 8] = lo;
        }
        __syncthreads();

        {
            const int dt = w;
#pragma unroll
            for (int at = 0; at < 3; at++) {
                f32x4 a4 = acc3[at];
#pragma unroll
                for (int p = 0; p < 4; p++) {
                    int a = at * 16 + kg * 4 + p;
                    float rs = (a < A_) ? resc[a] : 0.f;
                    a4[p] *= rs;
                }
#pragma unroll
                for (int ks2 = 0; ks2 < 2; ks2++) {
                    short8v ph = *(const short8v*)&KFh[((at * 2 + ks2) * 64 + lane) * 8];
                    short8v pll = *(const short8v*)&KFl[((at * 2 + ks2) * 64 + lane) * 8];
                    short8v vh = *(const short8v*)&VTh[((dt * 2 + ks2) * 64 + lane) * 8];
                    short8v vl = *(const short8v*)&VTl[((dt * 2 + ks2) * 64 + lane) * 8];
                    a4 = __builtin_amdgcn_mfma_f32_16x16x32_bf16(ph, vh, a4, 0, 0, 0);
                    a4 = __builtin_amdgcn_mfma_f32_16x16x32_bf16(pll, vh, a4, 0, 0, 0);
                    a4 = __builtin_amdgcn_mfma_f32_16x16x32_bf16(ph, vl, a4, 0, 0, 0);
                }
                acc3[at] = a4;
            }
        }
    }
    __syncthreads();

    {
        const int dt = w;
#pragma unroll
        for (int at = 0; at < 3; at++) {
#pragma unroll
            for (int p = 0; p < 4; p++) {
                int a = at * 16 + kg * 4 + p;
                if (a < A_)
                    Pacc[(((size_t)(bh * CH1 + q) * A_) + a) * D_ + dt * 16 + fr] = acc3[at][p];
            }
        }
    }
    if (t < A_) {
        Pm[(size_t)(bh * CH1 + q) * A_ + t] = mrow[t];
        Pl[(size_t)(bh * CH1 + q) * A_ + t] = lrow[t];
    }
}

// ---------------- stage 1 reduce ----------------
__global__ __launch_bounds__(256) void stage1_reduce(
    const float* __restrict__ Pacc, const float* __restrict__ Pm,
    const float* __restrict__ Pl, float* __restrict__ AgV)
{
    const int bh = blockIdx.x;
    const int t = threadIdx.x;
    __shared__ float F[CH1][A_], Linv[A_];
    if (t < A_) {
        float M = -INFINITY;
#pragma unroll
        for (int q = 0; q < CH1; q++) M = fmaxf(M, Pm[(size_t)(bh * CH1 + q) * A_ + t]);
        float L = 0.0f;
#pragma unroll
        for (int q = 0; q < CH1; q++) {
            float f = __expf(Pm[(size_t)(bh * CH1 + q) * A_ + t] - M);
            F[q][t] = f;
            L = fmaf(f, Pl[(size_t)(bh * CH1 + q) * A_ + t], L);
        }
        Linv[t] = 1.0f / L;
    }
    __syncthreads();
#pragma unroll
    for (int ii = 0; ii < 3; ii++) {
        int i = t + ii * 256;
        if (i < A_ * 16) {
            int a = i >> 4, d4 = i & 15;
            float4 s4 = make_float4(0.f, 0.f, 0.f, 0.f);
            for (int q = 0; q < CH1; q++) {
                float f = F[q][a];
                float4 p4 = *(const float4*)&Pacc[(((size_t)(bh * CH1 + q) * A_) + a) * D_ + d4 * 4];
                s4.x = fmaf(f, p4.x, s4.x);
                s4.y = fmaf(f, p4.y, s4.y);
                s4.z = fmaf(f, p4.z, s4.z);
                s4.w = fmaf(f, p4.w, s4.w);
            }
            float inv = Linv[a];
            s4.x *= inv; s4.y *= inv; s4.z *= inv; s4.w *= inv;
            *(float4*)&AgV[(size_t)bh * (A_ * D_) + a * D_ + d4 * 4] = s4;
        }
    }
}

// ------- stage 2 MFMA v4: 4 chunks/block, pipelined Q, hoisted AG frags ------
__global__ __launch_bounds__(256, 2) void stage2_mfma(
    const float* __restrict__ Qg,
    const unsigned short* __restrict__ AGFh, const unsigned short* __restrict__ AGFl,
    const unsigned short* __restrict__ DFh,  const unsigned short* __restrict__ DFl,
    const unsigned short* __restrict__ AVFh, const unsigned short* __restrict__ AVFl,
    float* __restrict__ Out)
{
    const int sb8 = blockIdx.x;      // 0..7 (4 chunks of 64 s)
    const int bh  = blockIdx.y;      // 0..191
    const int b = bh / H_, h = bh % H_;

    __shared__ unsigned short Qfh[8 * 64 * 8], Qfl[8 * 64 * 8];
    __shared__ float scm[64][52];
    __shared__ float scp[64][68];
    __shared__ unsigned short PAh[64][72], PAl[64][72];

    const int t = threadIdx.x;
    const int lane = t & 63, ts = t >> 6;
    const int fr = lane & 15, kg = lane >> 4;

    // hoisted AG fragments (bh-only, loop-invariant)
    short8v agh[3][2], agl[3][2];
#pragma unroll
    for (int at = 0; at < 3; at++)
#pragma unroll
        for (int ks = 0; ks < 2; ks++) {
            size_t o = ((((size_t)bh * 3 + at) * 2 + ks) * 64 + lane) * 8;
            agh[at][ks] = *(const short8v*)&AGFh[o];
            agl[at][ks] = *(const short8v*)&AGFl[o];
        }

    // Q staging geometry (v3-proven)
    const int r = t >> 2, c0 = (t & 3) * 16;
    const int tsr = r >> 4, frr = r & 15;
    const int c8a = (t & 3) * 2, c8b = c8a + 1;
    const int oa = ((tsr * 2 + (c8a >> 2)) * 64 + (((c8a & 3) << 4) | frr)) * 8;
    const int ob = ((tsr * 2 + (c8b >> 2)) * 64 + (((c8b & 3) << 4) | frr)) * 8;
    const float* qbase = Qg + ((size_t)bh * S_ + sb8 * 256 + r) * D_ + c0;

    // prologue: stage chunk 0
    {
        float4 f0 = *(const float4*)(qbase);
        float4 f1 = *(const float4*)(qbase + 4);
        float4 f2 = *(const float4*)(qbase + 8);
        float4 f3 = *(const float4*)(qbase + 12);
        float xa[8] = {f0.x, f0.y, f0.z, f0.w, f1.x, f1.y, f1.z, f1.w};
        float xb[8] = {f2.x, f2.y, f2.z, f2.w, f3.x, f3.y, f3.z, f3.w};
        int4 h0, l0, h1, l1;
        split8c(xa, h0, l0);
        split8c(xb, h1, l1);
        *(int4*)&Qfh[oa] = h0;  *(int4*)&Qfl[oa] = l0;
        *(int4*)&Qfh[ob] = h1;  *(int4*)&Qfl[ob] = l1;
    }
    __syncthreads();

    for (int c = 0; c < 4; c++) {
        const int s0 = sb8 * 256 + c * 64;
        const int base_u = (s0 >> 4) + 125;

        // q fragments from LDS (Qf for chunk c is ready)
        short8v qh[2], ql[2];
#pragma unroll
        for (int ks = 0; ks < 2; ks++) {
            qh[ks] = *(const short8v*)&Qfh[((ts * 2 + ks) * 64 + lane) * 8];
            ql[ks] = *(const short8v*)&Qfl[((ts * 2 + ks) * 64 + lane) * 8];
        }
        // issue next chunk's Q loads early (HBM latency hides under scores)
        float4 nf0, nf1, nf2, nf3;
        if (c < 3) {
            const float* np = qbase + (size_t)(c + 1) * 64 * D_;
            nf0 = *(const float4*)(np);
            nf1 = *(const float4*)(np + 4);
            nf2 = *(const float4*)(np + 8);
            nf3 = *(const float4*)(np + 12);
        }

        // ---- scores: AG (hoisted frags) ----
#pragma unroll
        for (int at = 0; at < 3; at++) {
            f32x4 acc = (f32x4){0.f, 0.f, 0.f, 0.f};
#pragma unroll
            for (int ks = 0; ks < 2; ks++) {
                acc = __builtin_amdgcn_mfma_f32_16x16x32_bf16(agh[at][ks], qh[ks], acc, 0, 0, 0);
                acc = __builtin_amdgcn_mfma_f32_16x16x32_bf16(agl[at][ks], qh[ks], acc, 0, 0, 0);
                acc = __builtin_amdgcn_mfma_f32_16x16x32_bf16(agh[at][ks], ql[ks], acc, 0, 0, 0);
            }
            *(f32x4*)&scm[ts * 16 + fr][at * 16 + kg * 4] = acc;
        }
        // ---- scores: PE band ----
#pragma unroll
        for (int o4 = 0; o4 < 4; o4++) {
            f32x4 acc = (f32x4){0.f, 0.f, 0.f, 0.f};
            const int u = base_u + ts + o4;
#pragma unroll
            for (int ks = 0; ks < 2; ks++) {
                size_t o = (((size_t)u * 2 + ks) * 64 + lane) * 8;
                short8v chv = *(const short8v*)&DFh[o];
                short8v clv = *(const short8v*)&DFl[o];
                acc = __builtin_amdgcn_mfma_f32_16x16x32_bf16(chv, qh[ks], acc, 0, 0, 0);
                acc = __builtin_amdgcn_mfma_f32_16x16x32_bf16(clv, qh[ks], acc, 0, 0, 0);
                acc = __builtin_amdgcn_mfma_f32_16x16x32_bf16(chv, ql[ks], acc, 0, 0, 0);
            }
            *(f32x4*)&scp[ts * 16 + fr][o4 * 16 + kg * 4] = acc;
        }
        __syncthreads();   // scores ready; Qf dead

        // ---- write next Qf (overlapped with softmax phase) ----
        if (c < 3) {
            float xa[8] = {nf0.x, nf0.y, nf0.z, nf0.w, nf1.x, nf1.y, nf1.z, nf1.w};
            float xb[8] = {nf2.x, nf2.y, nf2.z, nf2.w, nf3.x, nf3.y, nf3.z, nf3.w};
            int4 h0, l0, h1, l1;
            split8c(xa, h0, l0);
            split8c(xb, h1, l1);
            *(int4*)&Qfh[oa] = h0;  *(int4*)&Qfl[oa] = l0;
            *(int4*)&Qfh[ob] = h1;  *(int4*)&Qfl[ob] = l1;
        }
        // ---- softmax over a (4 threads per s-row) ----
        {
            const int rr = t >> 2, dq = t & 3;
            const int base = (rr & 15) + 39;
            float val[10];
#pragma unroll
            for (int i = 0; i < 10; i++) {
                int a = dq * 10 + i;
                val[i] = scm[rr][a] + scp[rr][base - a];
            }
            float mx = -INFINITY;
#pragma unroll
            for (int i = 0; i < 10; i++) mx = fmaxf(mx, val[i]);
            mx = fmaxf(mx, __shfl_xor(mx, 1));
            mx = fmaxf(mx, __shfl_xor(mx, 2));
            float sum = 0.f;
#pragma unroll
            for (int i = 0; i < 10; i++) { val[i] = __expf(val[i] - mx); sum += val[i]; }
            sum += __shfl_xor(sum, 1);
            sum += __shfl_xor(sum, 2);
            float inv = 1.0f / sum;
            unsigned* ph = (unsigned*)&PAh[rr][0];
            unsigned* pl = (unsigned*)&PAl[rr][0];
#pragma unroll
            for (int i = 0; i < 5; i++) {
                unsigned short h0, l0, h1, l1;
                split1(val[2 * i] * inv, h0, l0);
                split1(val[2 * i + 1] * inv, h1, l1);
                ph[dq * 5 + i] = (unsigned)h0 | ((unsigned)h1 << 16);
                pl[dq * 5 + i] = (unsigned)l0 | ((unsigned)l1 << 16);
            }
#pragma unroll
            for (int i = 0; i < 3; i++) { ph[20 + dq * 3 + i] = 0u; pl[20 + dq * 3 + i] = 0u; }
        }
        __syncthreads();   // PA ready; Qf[c+1] ready

        // ---- PV + store ----
        short8v ph8[2], pl8[2];
#pragma unroll
        for (int ks = 0; ks < 2; ks++) {
            ph8[ks] = *(const short8v*)&PAh[ts * 16 + fr][ks * 32 + kg * 8];
            pl8[ks] = *(const short8v*)&PAl[ts * 16 + fr][ks * 32 + kg * 8];
        }
#pragma unroll
        for (int nt = 0; nt < 4; nt++) {
            f32x4 acc = (f32x4){0.f, 0.f, 0.f, 0.f};
#pragma unroll
            for (int ks = 0; ks < 2; ks++) {
                size_t o = ((((size_t)bh * 4 + nt) * 2 + ks) * 64 + lane) * 8;
                short8v vh = *(const short8v*)&AVFh[o];
                short8v vl = *(const short8v*)&AVFl[o];
                acc = __builtin_amdgcn_mfma_f32_16x16x32_bf16(ph8[ks], vh, acc, 0, 0, 0);
                acc = __builtin_amdgcn_mfma_f32_16x16x32_bf16(pl8[ks], vh, acc, 0, 0, 0);
                acc = __builtin_amdgcn_mfma_f32_16x16x32_bf16(ph8[ks], vl, acc, 0, 0, 0);
            }
            const int d = nt * 16 + fr;
            float* op = Out + ((size_t)b * S_ + s0 + ts * 16 + kg * 4) * HID + h * D_ + d;
#pragma unroll
            for (int rr = 0; rr < 4; rr++)
                op[(size_t)rr * HID] = acc[rr];
        }
        __syncthreads();   // PA/scm/scp dead before next chunk's scores
    }
}

extern "C" void kernel_launch(void* const* d_in, const int* in_sizes, int n_in,
                              void* d_out, int out_size, void* d_ws, size_t ws_size,
                              hipStream_t stream) {
    const float* hs   = (const float*)d_in[0];
    const float* mask = (const float*)d_in[1];
    const float* Wq   = (const float*)d_in[2];
    const float* bq   = (const float*)d_in[3];
    const float* Wk   = (const float*)d_in[4];
    const float* bk   = (const float*)d_in[5];
    const float* Wv   = (const float*)d_in[6];
    const float* bv   = (const float*)d_in[7];
    const float* dist = (const float*)d_in[8];
    float* out = (float*)d_out;

    float* ws = (float*)d_ws;
    const size_t QKV = (size_t)B_ * H_ * S_ * D_;
    const size_t AG  = (size_t)B_ * H_ * A_ * D_;
    float* Q     = ws;
    float* K     = ws + QKV;
    float* V     = ws + 2 * QKV;
    float* Agent = ws + 3 * QKV;
    float* AgV   = Agent + AG;
    float* Pacc  = AgV + AG;
    float* Pm    = Pacc + (size_t)B_ * H_ * CH1 * A_ * D_;
    float* Pl    = Pm + (size_t)B_ * H_ * CH1 * A_;
    unsigned short* Wth = (unsigned short*)(Pl + (size_t)B_ * H_ * CH1 * A_);
    unsigned short* Wtl = Wth + (size_t)3 * HID * HID;
    unsigned short* DFh = Wtl + (size_t)3 * HID * HID;
    unsigned short* DFl = DFh + (size_t)262144;
    unsigned short* AGFh = DFl + (size_t)262144;
    unsigned short* AGFl = AGFh + (size_t)589824;
    unsigned short* AVFh = AGFl + (size_t)589824;
    unsigned short* AVFl = AVFh + (size_t)786432;
    unsigned short* AG1h = AVFl + (size_t)786432;
    unsigned short* AG1l = AG1h + (size_t)589824;
    unsigned short* D0h  = AG1l + (size_t)589824;
    unsigned short* D0l  = D0h + (size_t)134144;
    // total ws ~340 MB (within known-good <=393 MB budget)

    wt_convert<<<(3 * 192 * 768 + 255) / 256, 256, 0, stream>>>(Wq, Wk, Wv, Wth, Wtl);
    dist_frag<<<(256 * 2 * 64 + 255) / 256, 256, 0, stream>>>(dist, DFh, DFl);
    dist_frag0<<<(131 * 2 * 64 + 255) / 256, 256, 0, stream>>>(dist, D0h, D0l);
    qkv_z<<<2304, 512, 0, stream>>>(hs, Wth, Wtl, bq, bk, bv, Q, K, V);
    agent_pool<<<(B_ * H_ * A_ * D_ + 255) / 256, 256, 0, stream>>>(Q, Agent);
    ag_frag<<<(192 * 3 * 2 * 64 + 255) / 256, 256, 0, stream>>>(Agent, AGFh, AGFl, SCALE_);
    ag_frag<<<(192 * 3 * 2 * 64 + 255) / 256, 256, 0, stream>>>(Agent, AG1h, AG1l, 1.0f);
    dim3 g1(CH1, B_ * H_);
    stage1_mfma<<<g1, 256, 0, stream>>>(K, V, AG1h, AG1l, D0h, D0l, mask, Pacc, Pm, Pl);
    stage1_reduce<<<B_ * H_, 256, 0, stream>>>(Pacc, Pm, Pl, AgV);
    avt_frag<<<(192 * 4 * 2 * 64 + 255) / 256, 256, 0, stream>>>(AgV, AVFh, AVFl);
    dim3 g2(8, B_ * H_);
    stage2_mfma<<<g2, 256, 0, stream>>>(Q, AGFh, AGFl, DFh, DFl, AVFh, AVFl, out);
}